// Round 1
// baseline (2345.921 us; speedup 1.0000x reference)
//
#include <hip/hip_runtime.h>
#include <math.h>

#define N_NODES 100000
#define NE      1200000
#define D       64
#define H2      32
#define BN_EPS  1e-5f

// ---------------------------------------------------------------------------
// Edge scatter: for each edge e, agg[dst[e]] += feat[src[e]] (64 f32),
// optionally cnt[dst[e]] += 1.  16 threads per edge, float4 per thread.
// ---------------------------------------------------------------------------
__global__ __launch_bounds__(256) void scatter_kernel(
    const float* __restrict__ feat,
    const int* __restrict__ src,
    const int* __restrict__ dst,
    float* __restrict__ agg,
    float* __restrict__ cnt,   // nullptr on the second pass
    int nE) {
  int t = blockIdx.x * 256 + threadIdx.x;
  int e = t >> 4;
  int fq = t & 15;
  if (e >= nE) return;
  int s = src[e];
  int d0 = dst[e];
  const float4 v = *reinterpret_cast<const float4*>(feat + (size_t)s * D + fq * 4);
  float* base = agg + (size_t)d0 * D + fq * 4;
  atomicAdd(base + 0, v.x);
  atomicAdd(base + 1, v.y);
  atomicAdd(base + 2, v.z);
  atomicAdd(base + 3, v.w);
  if (cnt != nullptr && fq == 0) atomicAdd(cnt + d0, 1.0f);
}

// ---------------------------------------------------------------------------
// Layer 1 node kernel: h1 = relu(bn1(Wl1 @ (agg/cnt) + bl1 + Wr1 @ x))
// One thread per node; weights staged in LDS (broadcast reads).
// BN folded: y = lin*scale + shift, scale=g*rsqrt(v+eps),
// shift=(bl-m)*scale+beta.
// ---------------------------------------------------------------------------
__global__ __launch_bounds__(256) void layer1_kernel(
    const float* __restrict__ x, const float* __restrict__ agg,
    const float* __restrict__ cnt,
    const float* __restrict__ Wl, const float* __restrict__ bl,
    const float* __restrict__ Wr,
    const float* __restrict__ g, const float* __restrict__ beta,
    const float* __restrict__ m, const float* __restrict__ v,
    float* __restrict__ h1) {
  __shared__ float Wls[D * D];
  __shared__ float Wrs[D * D];
  __shared__ float scale_s[D];
  __shared__ float shift_s[D];
  int tid = threadIdx.x;
  for (int i = tid; i < D * D; i += 256) {
    Wls[i] = Wl[i];
    Wrs[i] = Wr[i];
  }
  if (tid < D) {
    float s = g[tid] * rsqrtf(v[tid] + BN_EPS);
    scale_s[tid] = s;
    shift_s[tid] = (bl[tid] - m[tid]) * s + beta[tid];
  }
  __syncthreads();

  int node = blockIdx.x * 256 + tid;
  if (node >= N_NODES) return;

  float acc[D];
#pragma unroll
  for (int d = 0; d < D; ++d) acc[d] = 0.f;

  float inv = 1.0f / fmaxf(cnt[node], 1.0f);
  const float4* xr = reinterpret_cast<const float4*>(x + (size_t)node * D);
  const float4* ar = reinterpret_cast<const float4*>(agg + (size_t)node * D);

#pragma unroll 1
  for (int kq = 0; kq < D / 4; ++kq) {
    float4 xv = xr[kq];
    float4 av = ar[kq];
    av.x *= inv; av.y *= inv; av.z *= inv; av.w *= inv;
    int k = kq * 4;
#pragma unroll
    for (int d = 0; d < D; ++d) {
      const float4 wl = *reinterpret_cast<const float4*>(&Wls[d * D + k]);
      const float4 wr = *reinterpret_cast<const float4*>(&Wrs[d * D + k]);
      acc[d] += wl.x * av.x + wl.y * av.y + wl.z * av.z + wl.w * av.w
              + wr.x * xv.x + wr.y * xv.y + wr.z * xv.z + wr.w * xv.w;
    }
  }

  float4* out = reinterpret_cast<float4*>(h1 + (size_t)node * D);
#pragma unroll
  for (int dq = 0; dq < D / 4; ++dq) {
    float4 o;
    o.x = fmaxf(acc[dq * 4 + 0] * scale_s[dq * 4 + 0] + shift_s[dq * 4 + 0], 0.f);
    o.y = fmaxf(acc[dq * 4 + 1] * scale_s[dq * 4 + 1] + shift_s[dq * 4 + 1], 0.f);
    o.z = fmaxf(acc[dq * 4 + 2] * scale_s[dq * 4 + 2] + shift_s[dq * 4 + 2], 0.f);
    o.w = fmaxf(acc[dq * 4 + 3] * scale_s[dq * 4 + 3] + shift_s[dq * 4 + 3], 0.f);
    out[dq] = o;
  }
}

// ---------------------------------------------------------------------------
// Layer 2 node kernel + MLP head + sigmoid.
// ---------------------------------------------------------------------------
__global__ __launch_bounds__(256) void layer2_kernel(
    const float* __restrict__ h1, const float* __restrict__ agg,
    const float* __restrict__ cnt,
    const float* __restrict__ Wl, const float* __restrict__ bl,
    const float* __restrict__ Wr,
    const float* __restrict__ g, const float* __restrict__ beta,
    const float* __restrict__ m, const float* __restrict__ v,
    const float* __restrict__ mW1, const float* __restrict__ mb1,
    const float* __restrict__ mW2, const float* __restrict__ mb2,
    float* __restrict__ out) {
  __shared__ float Wls[D * D];
  __shared__ float Wrs[D * D];
  __shared__ float mW1s[H2 * D];
  __shared__ float scale_s[D];
  __shared__ float shift_s[D];
  __shared__ float mW2s[H2];
  __shared__ float mb1s[H2];
  int tid = threadIdx.x;
  for (int i = tid; i < D * D; i += 256) {
    Wls[i] = Wl[i];
    Wrs[i] = Wr[i];
  }
  for (int i = tid; i < H2 * D; i += 256) mW1s[i] = mW1[i];
  if (tid < D) {
    float s = g[tid] * rsqrtf(v[tid] + BN_EPS);
    scale_s[tid] = s;
    shift_s[tid] = (bl[tid] - m[tid]) * s + beta[tid];
  }
  if (tid < H2) {
    mW2s[tid] = mW2[tid];
    mb1s[tid] = mb1[tid];
  }
  __syncthreads();

  int node = blockIdx.x * 256 + tid;
  if (node >= N_NODES) return;

  float acc[D];
#pragma unroll
  for (int d = 0; d < D; ++d) acc[d] = 0.f;

  float inv = 1.0f / fmaxf(cnt[node], 1.0f);
  const float4* xr = reinterpret_cast<const float4*>(h1 + (size_t)node * D);
  const float4* ar = reinterpret_cast<const float4*>(agg + (size_t)node * D);

#pragma unroll 1
  for (int kq = 0; kq < D / 4; ++kq) {
    float4 xv = xr[kq];
    float4 av = ar[kq];
    av.x *= inv; av.y *= inv; av.z *= inv; av.w *= inv;
    int k = kq * 4;
#pragma unroll
    for (int d = 0; d < D; ++d) {
      const float4 wl = *reinterpret_cast<const float4*>(&Wls[d * D + k]);
      const float4 wr = *reinterpret_cast<const float4*>(&Wrs[d * D + k]);
      acc[d] += wl.x * av.x + wl.y * av.y + wl.z * av.z + wl.w * av.w
              + wr.x * xv.x + wr.y * xv.y + wr.z * xv.z + wr.w * xv.w;
    }
  }

  // BN2 + ReLU in place
#pragma unroll
  for (int d = 0; d < D; ++d)
    acc[d] = fmaxf(acc[d] * scale_s[d] + shift_s[d], 0.f);

  // MLP head: z = relu(mW1 @ acc + mb1) [32]; o = mW2 @ z + mb2; sigmoid
  float o = mb2[0];
#pragma unroll 1
  for (int j = 0; j < H2; ++j) {
    float zj = mb1s[j];
#pragma unroll
    for (int dq = 0; dq < D / 4; ++dq) {
      const float4 w = *reinterpret_cast<const float4*>(&mW1s[j * D + dq * 4]);
      zj += w.x * acc[dq * 4 + 0] + w.y * acc[dq * 4 + 1]
          + w.z * acc[dq * 4 + 2] + w.w * acc[dq * 4 + 3];
    }
    o += mW2s[j] * fmaxf(zj, 0.f);
  }
  out[node] = 1.0f / (1.0f + expf(-o));
}

// ---------------------------------------------------------------------------
extern "C" void kernel_launch(void* const* d_in, const int* in_sizes, int n_in,
                              void* d_out, int out_size, void* d_ws, size_t ws_size,
                              hipStream_t stream) {
  const float* x    = (const float*)d_in[0];
  const int*   ei   = (const int*)d_in[1];     // [2, E] int32
  const float* Wl1  = (const float*)d_in[2];
  const float* bl1  = (const float*)d_in[3];
  const float* Wr1  = (const float*)d_in[4];
  const float* g1   = (const float*)d_in[5];
  const float* be1  = (const float*)d_in[6];
  const float* m1   = (const float*)d_in[7];
  const float* v1   = (const float*)d_in[8];
  const float* Wl2  = (const float*)d_in[9];
  const float* bl2  = (const float*)d_in[10];
  const float* Wr2  = (const float*)d_in[11];
  const float* g2   = (const float*)d_in[12];
  const float* be2  = (const float*)d_in[13];
  const float* m2   = (const float*)d_in[14];
  const float* v2   = (const float*)d_in[15];
  const float* mW1  = (const float*)d_in[16];
  const float* mb1  = (const float*)d_in[17];
  const float* mW2  = (const float*)d_in[18];
  const float* mb2  = (const float*)d_in[19];
  float* out = (float*)d_out;

  const int* src = ei;         // row 0
  const int* dst = ei + NE;    // row 1

  // Workspace layout: agg [N*D] | cnt [N] | h1 [N*D]
  float* agg = (float*)d_ws;
  float* cnt = agg + (size_t)N_NODES * D;
  float* h1  = cnt + N_NODES;

  const size_t zero1_bytes = ((size_t)N_NODES * D + N_NODES) * sizeof(float);
  const size_t zero2_bytes = (size_t)N_NODES * D * sizeof(float);

  const int scatter_blocks = (NE * 16 + 255) / 256;
  const int node_blocks = (N_NODES + 255) / 256;

  // --- layer 1 ---
  hipMemsetAsync(d_ws, 0, zero1_bytes, stream);  // agg + cnt
  scatter_kernel<<<scatter_blocks, 256, 0, stream>>>(x, src, dst, agg, cnt, NE);
  layer1_kernel<<<node_blocks, 256, 0, stream>>>(x, agg, cnt, Wl1, bl1, Wr1,
                                                 g1, be1, m1, v1, h1);
  // --- layer 2 ---
  hipMemsetAsync(agg, 0, zero2_bytes, stream);   // re-zero agg
  scatter_kernel<<<scatter_blocks, 256, 0, stream>>>(h1, src, dst, agg, nullptr, NE);
  layer2_kernel<<<node_blocks, 256, 0, stream>>>(h1, agg, cnt, Wl2, bl2, Wr2,
                                                 g2, be2, m2, v2,
                                                 mW1, mb1, mW2, mb2, out);
}

// Round 2
// 532.164 us; speedup vs baseline: 4.4083x; 4.4083x over previous
//
#include <hip/hip_runtime.h>
#include <math.h>

#define N_NODES 100000
#define NE      1200000
#define D       64
#define H2      32
#define BN_EPS  1e-5f
#define SCAN_B  512

// ---------------------------------------------------------------------------
// CSR build: histogram of dst into row_start[1+d], blocked inclusive scan,
// cursor fill producing src_sorted grouped by destination node.
// ---------------------------------------------------------------------------
__global__ __launch_bounds__(256) void hist_kernel(const int* __restrict__ dst,
                                                   int* __restrict__ row_start) {
  int e = blockIdx.x * 256 + threadIdx.x;
  if (e < NE) atomicAdd(&row_start[1 + dst[e]], 1);
}

__global__ __launch_bounds__(SCAN_B) void scan_part(int* __restrict__ a,
                                                    int* __restrict__ bsum, int n) {
  __shared__ int s[SCAN_B];
  int i = blockIdx.x * SCAN_B + threadIdx.x;
  int v = (i < n) ? a[i] : 0;
  s[threadIdx.x] = v;
  __syncthreads();
  for (int off = 1; off < SCAN_B; off <<= 1) {
    int t = (threadIdx.x >= off) ? s[threadIdx.x - off] : 0;
    __syncthreads();
    s[threadIdx.x] += t;
    __syncthreads();
  }
  if (i < n) a[i] = s[threadIdx.x];
  if (threadIdx.x == SCAN_B - 1) bsum[blockIdx.x] = s[SCAN_B - 1];
}

__global__ __launch_bounds__(256) void scan_mid(int* __restrict__ bsum, int nb) {
  __shared__ int s[256];
  int v = (threadIdx.x < nb) ? bsum[threadIdx.x] : 0;
  s[threadIdx.x] = v;
  __syncthreads();
  for (int off = 1; off < 256; off <<= 1) {
    int t = (threadIdx.x >= off) ? s[threadIdx.x - off] : 0;
    __syncthreads();
    s[threadIdx.x] += t;
    __syncthreads();
  }
  if (threadIdx.x < nb) bsum[threadIdx.x] = s[threadIdx.x];
}

__global__ __launch_bounds__(SCAN_B) void scan_add(int* __restrict__ a,
                                                   const int* __restrict__ bsum,
                                                   int n, int* __restrict__ nxt) {
  int i = blockIdx.x * SCAN_B + threadIdx.x;
  if (i >= n) return;
  int add = (blockIdx.x > 0) ? bsum[blockIdx.x - 1] : 0;
  int val = a[i] + add;
  a[i] = val;
  if (i < N_NODES) nxt[i] = val;   // exclusive start = cursor init
}

__global__ __launch_bounds__(256) void fill_kernel(const int* __restrict__ src,
                                                   const int* __restrict__ dst,
                                                   int* __restrict__ nxt,
                                                   int* __restrict__ col) {
  int e = blockIdx.x * 256 + threadIdx.x;
  if (e >= NE) return;
  int p = atomicAdd(&nxt[dst[e]], 1);
  col[p] = src[e];
}

// ---------------------------------------------------------------------------
// Gather-aggregate: one wave per node, lane = feature column. Reads coalesced
// 256B rows of feat for each in-edge, accumulates in a register, writes MEAN.
// ---------------------------------------------------------------------------
__global__ __launch_bounds__(256) void aggregate_kernel(
    const float* __restrict__ feat, const int* __restrict__ row_start,
    const int* __restrict__ col, float* __restrict__ aggout) {
  int w = threadIdx.x >> 6;
  int lane = threadIdx.x & 63;
  int node = blockIdx.x * 4 + w;
  if (node >= N_NODES) return;
  int r0 = row_start[node];
  int r1 = row_start[node + 1];
  float sum = 0.f;
  int j = r0;
  for (; j + 1 < r1; j += 2) {
    int s0 = col[j];
    int s1 = col[j + 1];
    sum += feat[s0 * D + lane] + feat[s1 * D + lane];
  }
  if (j < r1) sum += feat[col[j] * D + lane];
  float inv = 1.f / fmaxf((float)(r1 - r0), 1.f);
  aggout[node * D + lane] = sum * inv;
}

// ---------------------------------------------------------------------------
// Layer 1: h1 = relu(bn1(Wl1 @ mean + bl1 + Wr1 @ x)); mean precomputed.
// One thread per node; weights in LDS (uniform broadcast reads).
// ---------------------------------------------------------------------------
__global__ __launch_bounds__(256) void layer1_kernel(
    const float* __restrict__ x, const float* __restrict__ mean,
    const float* __restrict__ Wl, const float* __restrict__ bl,
    const float* __restrict__ Wr,
    const float* __restrict__ g, const float* __restrict__ beta,
    const float* __restrict__ m, const float* __restrict__ v,
    float* __restrict__ h1) {
  __shared__ float Wls[D * D];
  __shared__ float Wrs[D * D];
  __shared__ float scale_s[D];
  __shared__ float shift_s[D];
  int tid = threadIdx.x;
  for (int i = tid; i < D * D; i += 256) {
    Wls[i] = Wl[i];
    Wrs[i] = Wr[i];
  }
  if (tid < D) {
    float s = g[tid] * rsqrtf(v[tid] + BN_EPS);
    scale_s[tid] = s;
    shift_s[tid] = (bl[tid] - m[tid]) * s + beta[tid];
  }
  __syncthreads();

  int node = blockIdx.x * 256 + tid;
  if (node >= N_NODES) return;

  float acc[D];
#pragma unroll
  for (int d = 0; d < D; ++d) acc[d] = 0.f;

  const float4* xr = reinterpret_cast<const float4*>(x + (size_t)node * D);
  const float4* ar = reinterpret_cast<const float4*>(mean + (size_t)node * D);

#pragma unroll 1
  for (int kq = 0; kq < D / 4; ++kq) {
    float4 xv = xr[kq];
    float4 av = ar[kq];
    int k = kq * 4;
#pragma unroll
    for (int d = 0; d < D; ++d) {
      const float4 wl = *reinterpret_cast<const float4*>(&Wls[d * D + k]);
      const float4 wr = *reinterpret_cast<const float4*>(&Wrs[d * D + k]);
      acc[d] += wl.x * av.x + wl.y * av.y + wl.z * av.z + wl.w * av.w
              + wr.x * xv.x + wr.y * xv.y + wr.z * xv.z + wr.w * xv.w;
    }
  }

  float4* out = reinterpret_cast<float4*>(h1 + (size_t)node * D);
#pragma unroll
  for (int dq = 0; dq < D / 4; ++dq) {
    float4 o;
    o.x = fmaxf(acc[dq * 4 + 0] * scale_s[dq * 4 + 0] + shift_s[dq * 4 + 0], 0.f);
    o.y = fmaxf(acc[dq * 4 + 1] * scale_s[dq * 4 + 1] + shift_s[dq * 4 + 1], 0.f);
    o.z = fmaxf(acc[dq * 4 + 2] * scale_s[dq * 4 + 2] + shift_s[dq * 4 + 2], 0.f);
    o.w = fmaxf(acc[dq * 4 + 3] * scale_s[dq * 4 + 3] + shift_s[dq * 4 + 3], 0.f);
    out[dq] = o;
  }
}

// ---------------------------------------------------------------------------
// Layer 2 + MLP head + sigmoid.
// ---------------------------------------------------------------------------
__global__ __launch_bounds__(256) void layer2_kernel(
    const float* __restrict__ h1, const float* __restrict__ mean,
    const float* __restrict__ Wl, const float* __restrict__ bl,
    const float* __restrict__ Wr,
    const float* __restrict__ g, const float* __restrict__ beta,
    const float* __restrict__ m, const float* __restrict__ v,
    const float* __restrict__ mW1, const float* __restrict__ mb1,
    const float* __restrict__ mW2, const float* __restrict__ mb2,
    float* __restrict__ out) {
  __shared__ float Wls[D * D];
  __shared__ float Wrs[D * D];
  __shared__ float mW1s[H2 * D];
  __shared__ float scale_s[D];
  __shared__ float shift_s[D];
  __shared__ float mW2s[H2];
  __shared__ float mb1s[H2];
  int tid = threadIdx.x;
  for (int i = tid; i < D * D; i += 256) {
    Wls[i] = Wl[i];
    Wrs[i] = Wr[i];
  }
  for (int i = tid; i < H2 * D; i += 256) mW1s[i] = mW1[i];
  if (tid < D) {
    float s = g[tid] * rsqrtf(v[tid] + BN_EPS);
    scale_s[tid] = s;
    shift_s[tid] = (bl[tid] - m[tid]) * s + beta[tid];
  }
  if (tid < H2) {
    mW2s[tid] = mW2[tid];
    mb1s[tid] = mb1[tid];
  }
  __syncthreads();

  int node = blockIdx.x * 256 + tid;
  if (node >= N_NODES) return;

  float acc[D];
#pragma unroll
  for (int d = 0; d < D; ++d) acc[d] = 0.f;

  const float4* xr = reinterpret_cast<const float4*>(h1 + (size_t)node * D);
  const float4* ar = reinterpret_cast<const float4*>(mean + (size_t)node * D);

#pragma unroll 1
  for (int kq = 0; kq < D / 4; ++kq) {
    float4 xv = xr[kq];
    float4 av = ar[kq];
    int k = kq * 4;
#pragma unroll
    for (int d = 0; d < D; ++d) {
      const float4 wl = *reinterpret_cast<const float4*>(&Wls[d * D + k]);
      const float4 wr = *reinterpret_cast<const float4*>(&Wrs[d * D + k]);
      acc[d] += wl.x * av.x + wl.y * av.y + wl.z * av.z + wl.w * av.w
              + wr.x * xv.x + wr.y * xv.y + wr.z * xv.z + wr.w * xv.w;
    }
  }

#pragma unroll
  for (int d = 0; d < D; ++d)
    acc[d] = fmaxf(acc[d] * scale_s[d] + shift_s[d], 0.f);

  float o = mb2[0];
#pragma unroll 1
  for (int j = 0; j < H2; ++j) {
    float zj = mb1s[j];
#pragma unroll
    for (int dq = 0; dq < D / 4; ++dq) {
      const float4 w = *reinterpret_cast<const float4*>(&mW1s[j * D + dq * 4]);
      zj += w.x * acc[dq * 4 + 0] + w.y * acc[dq * 4 + 1]
          + w.z * acc[dq * 4 + 2] + w.w * acc[dq * 4 + 3];
    }
    o += mW2s[j] * fmaxf(zj, 0.f);
  }
  out[node] = 1.0f / (1.0f + expf(-o));
}

// ---------------------------------------------------------------------------
extern "C" void kernel_launch(void* const* d_in, const int* in_sizes, int n_in,
                              void* d_out, int out_size, void* d_ws, size_t ws_size,
                              hipStream_t stream) {
  const float* x    = (const float*)d_in[0];
  const int*   ei   = (const int*)d_in[1];     // [2, E] int32
  const float* Wl1  = (const float*)d_in[2];
  const float* bl1  = (const float*)d_in[3];
  const float* Wr1  = (const float*)d_in[4];
  const float* g1   = (const float*)d_in[5];
  const float* be1  = (const float*)d_in[6];
  const float* m1   = (const float*)d_in[7];
  const float* v1   = (const float*)d_in[8];
  const float* Wl2  = (const float*)d_in[9];
  const float* bl2  = (const float*)d_in[10];
  const float* Wr2  = (const float*)d_in[11];
  const float* g2   = (const float*)d_in[12];
  const float* be2  = (const float*)d_in[13];
  const float* m2   = (const float*)d_in[14];
  const float* v2   = (const float*)d_in[15];
  const float* mW1  = (const float*)d_in[16];
  const float* mb1  = (const float*)d_in[17];
  const float* mW2  = (const float*)d_in[18];
  const float* mb2  = (const float*)d_in[19];
  float* out = (float*)d_out;

  const int* src = ei;         // row 0
  const int* dst = ei + NE;    // row 1

  // ws layout (all 16B-aligned):
  //   row_start : N+32 ints      (N+1 used)
  //   src_sorted: NE ints
  //   agg       : N*D floats     (mean output of aggregate)
  //   h1        : N*D floats     (first N ints aliased as cursor during build,
  //                               next 256 ints as block sums for the scan)
  int* row_start  = (int*)d_ws;
  int* src_sorted = row_start + (N_NODES + 32);
  float* agg = (float*)(src_sorted + NE);
  float* h1  = agg + (size_t)N_NODES * D;
  int* nxt   = (int*)h1;
  int* bsum  = nxt + N_NODES + 32;

  const int n_scan = N_NODES + 1;
  const int scan_blocks = (n_scan + SCAN_B - 1) / SCAN_B;   // 196
  const int edge_blocks = (NE + 255) / 256;
  const int agg_blocks  = (N_NODES + 3) / 4;                // 1 wave per node
  const int node_blocks = (N_NODES + 255) / 256;

  // --- build CSR ---
  hipMemsetAsync(row_start, 0, (size_t)(N_NODES + 1) * sizeof(int), stream);
  hist_kernel<<<edge_blocks, 256, 0, stream>>>(dst, row_start);
  scan_part<<<scan_blocks, SCAN_B, 0, stream>>>(row_start, bsum, n_scan);
  scan_mid<<<1, 256, 0, stream>>>(bsum, scan_blocks);
  scan_add<<<scan_blocks, SCAN_B, 0, stream>>>(row_start, bsum, n_scan, nxt);
  fill_kernel<<<edge_blocks, 256, 0, stream>>>(src, dst, nxt, src_sorted);

  // --- layer 1 ---
  aggregate_kernel<<<agg_blocks, 256, 0, stream>>>(x, row_start, src_sorted, agg);
  layer1_kernel<<<node_blocks, 256, 0, stream>>>(x, agg, Wl1, bl1, Wr1,
                                                 g1, be1, m1, v1, h1);
  // --- layer 2 ---
  aggregate_kernel<<<agg_blocks, 256, 0, stream>>>(h1, row_start, src_sorted, agg);
  layer2_kernel<<<node_blocks, 256, 0, stream>>>(h1, agg, Wl2, bl2, Wr2,
                                                 g2, be2, m2, v2,
                                                 mW1, mb1, mW2, mb2, out);
}

// Round 3
// 453.023 us; speedup vs baseline: 5.1784x; 1.1747x over previous
//
#include <hip/hip_runtime.h>
#include <math.h>

#define N_NODES 100000
#define NE      1200000
#define D       64
#define H2      32
#define BN_EPS  1e-5f
#define SCAN_B  512

// ---- bf16 helpers (RNE) ----------------------------------------------------
__device__ __forceinline__ unsigned short f2bf(float f) {
  unsigned int u = __float_as_uint(f);
  u += 0x7fffu + ((u >> 16) & 1u);
  return (unsigned short)(u >> 16);
}
__device__ __forceinline__ float bflo(unsigned int u) { return __uint_as_float(u << 16); }
__device__ __forceinline__ float bfhi(unsigned int u) { return __uint_as_float(u & 0xffff0000u); }

// ---------------------------------------------------------------------------
// prep: rank+histogram of dst (atomics into row_start[1+d]), and convert
// x (f32) -> xh (bf16) with a grid-stride loop.
// ---------------------------------------------------------------------------
__global__ __launch_bounds__(256) void prep_kernel(
    const int* __restrict__ dst, int* __restrict__ row_start,
    int* __restrict__ rank,
    const float* __restrict__ x, unsigned short* __restrict__ xh) {
  int t = blockIdx.x * 256 + threadIdx.x;
  if (t < NE) rank[t] = atomicAdd(&row_start[1 + dst[t]], 1);
  const int nquads = N_NODES * D / 4;          // 1.6M float4 chunks
  const int stride = gridDim.x * 256;
  for (int i = t; i < nquads; i += stride) {
    float4 v = reinterpret_cast<const float4*>(x)[i];
    ushort4 o;
    o.x = f2bf(v.x); o.y = f2bf(v.y); o.z = f2bf(v.z); o.w = f2bf(v.w);
    reinterpret_cast<ushort4*>(xh)[i] = o;
  }
}

// ---------------------------------------------------------------------------
// Blocked scan over row_start[0..N] (inclusive over [0, c0, c1, ...] =
// exclusive edge starts).
// ---------------------------------------------------------------------------
__global__ __launch_bounds__(SCAN_B) void scan_part(int* __restrict__ a,
                                                    int* __restrict__ bsum, int n) {
  __shared__ int s[SCAN_B];
  int i = blockIdx.x * SCAN_B + threadIdx.x;
  int v = (i < n) ? a[i] : 0;
  s[threadIdx.x] = v;
  __syncthreads();
  for (int off = 1; off < SCAN_B; off <<= 1) {
    int t = (threadIdx.x >= off) ? s[threadIdx.x - off] : 0;
    __syncthreads();
    s[threadIdx.x] += t;
    __syncthreads();
  }
  if (i < n) a[i] = s[threadIdx.x];
  if (threadIdx.x == SCAN_B - 1) bsum[blockIdx.x] = s[SCAN_B - 1];
}

__global__ __launch_bounds__(256) void scan_mid(int* __restrict__ bsum, int nb) {
  __shared__ int s[256];
  int v = (threadIdx.x < nb) ? bsum[threadIdx.x] : 0;
  s[threadIdx.x] = v;
  __syncthreads();
  for (int off = 1; off < 256; off <<= 1) {
    int t = (threadIdx.x >= off) ? s[threadIdx.x - off] : 0;
    __syncthreads();
    s[threadIdx.x] += t;
    __syncthreads();
  }
  if (threadIdx.x < nb) bsum[threadIdx.x] = s[threadIdx.x];
}

__global__ __launch_bounds__(SCAN_B) void scan_add(int* __restrict__ a,
                                                   const int* __restrict__ bsum, int n) {
  int i = blockIdx.x * SCAN_B + threadIdx.x;
  if (i >= n || blockIdx.x == 0) return;
  a[i] += bsum[blockIdx.x - 1];
}

// ---------------------------------------------------------------------------
// fill: pure scatter, no atomics. col[row_start[dst]+rank] = src.
// ---------------------------------------------------------------------------
__global__ __launch_bounds__(256) void fill_kernel(const int* __restrict__ src,
                                                   const int* __restrict__ dst,
                                                   const int* __restrict__ rank,
                                                   const int* __restrict__ row_start,
                                                   int* __restrict__ col) {
  int e = blockIdx.x * 256 + threadIdx.x;
  if (e >= NE) return;
  col[row_start[dst[e]] + rank[e]] = src[e];
}

// ---------------------------------------------------------------------------
// Gather-aggregate (bf16 rows, 128B each). One wave per node. Lanes 0-31
// process even edges, 32-63 odd edges; each sub-lane owns 2 feature cols.
// Combine halves with shfl_xor(32); write bf16 mean.
// ---------------------------------------------------------------------------
__global__ __launch_bounds__(256) void aggregate_kernel(
    const unsigned short* __restrict__ feat, const int* __restrict__ row_start,
    const int* __restrict__ col, unsigned short* __restrict__ meanout) {
  int w = threadIdx.x >> 6;
  int lane = threadIdx.x & 63;
  int node = blockIdx.x * 4 + w;
  if (node >= N_NODES) return;
  int r0 = row_start[node];
  int r1 = row_start[node + 1];
  int half = lane >> 5;
  int sl = lane & 31;
  float ax = 0.f, ay = 0.f;
  for (int j = r0 + half; j < r1; j += 2) {
    int s = col[j];
    unsigned int u = *reinterpret_cast<const unsigned int*>(feat + s * D + 2 * sl);
    ax += bflo(u);
    ay += bfhi(u);
  }
  ax += __shfl_xor(ax, 32);
  ay += __shfl_xor(ay, 32);
  if (half == 0) {
    float inv = 1.f / fmaxf((float)(r1 - r0), 1.f);
    unsigned int o = (unsigned int)f2bf(ax * inv) | ((unsigned int)f2bf(ay * inv) << 16);
    reinterpret_cast<unsigned int*>(meanout + node * D)[sl] = o;
  }
}

// ---------------------------------------------------------------------------
// Layer 1: h1h = bf16(relu(bn1(Wl1 @ mean + bl1 + Wr1 @ x))). Thread/node.
// ---------------------------------------------------------------------------
__global__ __launch_bounds__(256) void layer1_kernel(
    const float* __restrict__ x, const unsigned short* __restrict__ meanh,
    const float* __restrict__ Wl, const float* __restrict__ bl,
    const float* __restrict__ Wr,
    const float* __restrict__ g, const float* __restrict__ beta,
    const float* __restrict__ m, const float* __restrict__ v,
    unsigned short* __restrict__ h1h) {
  __shared__ float Wls[D * D];
  __shared__ float Wrs[D * D];
  __shared__ float scale_s[D];
  __shared__ float shift_s[D];
  int tid = threadIdx.x;
  for (int i = tid; i < D * D; i += 256) {
    Wls[i] = Wl[i];
    Wrs[i] = Wr[i];
  }
  if (tid < D) {
    float s = g[tid] * rsqrtf(v[tid] + BN_EPS);
    scale_s[tid] = s;
    shift_s[tid] = (bl[tid] - m[tid]) * s + beta[tid];
  }
  __syncthreads();

  int node = blockIdx.x * 256 + tid;
  if (node >= N_NODES) return;

  float acc[D];
#pragma unroll
  for (int d = 0; d < D; ++d) acc[d] = 0.f;

  const float4* xr = reinterpret_cast<const float4*>(x + (size_t)node * D);
  const uint2* ar = reinterpret_cast<const uint2*>(meanh + (size_t)node * D);

#pragma unroll 1
  for (int kq = 0; kq < D / 4; ++kq) {
    float4 xv = xr[kq];
    uint2 a = ar[kq];
    float4 av;
    av.x = bflo(a.x); av.y = bfhi(a.x); av.z = bflo(a.y); av.w = bfhi(a.y);
    int k = kq * 4;
#pragma unroll
    for (int d = 0; d < D; ++d) {
      const float4 wl = *reinterpret_cast<const float4*>(&Wls[d * D + k]);
      const float4 wr = *reinterpret_cast<const float4*>(&Wrs[d * D + k]);
      acc[d] += wl.x * av.x + wl.y * av.y + wl.z * av.z + wl.w * av.w
              + wr.x * xv.x + wr.y * xv.y + wr.z * xv.z + wr.w * xv.w;
    }
  }

  ushort4* out = reinterpret_cast<ushort4*>(h1h + (size_t)node * D);
#pragma unroll
  for (int dq = 0; dq < D / 4; ++dq) {
    ushort4 o;
    o.x = f2bf(fmaxf(acc[dq * 4 + 0] * scale_s[dq * 4 + 0] + shift_s[dq * 4 + 0], 0.f));
    o.y = f2bf(fmaxf(acc[dq * 4 + 1] * scale_s[dq * 4 + 1] + shift_s[dq * 4 + 1], 0.f));
    o.z = f2bf(fmaxf(acc[dq * 4 + 2] * scale_s[dq * 4 + 2] + shift_s[dq * 4 + 2], 0.f));
    o.w = f2bf(fmaxf(acc[dq * 4 + 3] * scale_s[dq * 4 + 3] + shift_s[dq * 4 + 3], 0.f));
    out[dq] = o;
  }
}

// ---------------------------------------------------------------------------
// Layer 2 + MLP head + sigmoid. Own-node term and mean both bf16.
// ---------------------------------------------------------------------------
__global__ __launch_bounds__(256) void layer2_kernel(
    const unsigned short* __restrict__ h1h, const unsigned short* __restrict__ meanh,
    const float* __restrict__ Wl, const float* __restrict__ bl,
    const float* __restrict__ Wr,
    const float* __restrict__ g, const float* __restrict__ beta,
    const float* __restrict__ m, const float* __restrict__ v,
    const float* __restrict__ mW1, const float* __restrict__ mb1,
    const float* __restrict__ mW2, const float* __restrict__ mb2,
    float* __restrict__ out) {
  __shared__ float Wls[D * D];
  __shared__ float Wrs[D * D];
  __shared__ float mW1s[H2 * D];
  __shared__ float scale_s[D];
  __shared__ float shift_s[D];
  __shared__ float mW2s[H2];
  __shared__ float mb1s[H2];
  int tid = threadIdx.x;
  for (int i = tid; i < D * D; i += 256) {
    Wls[i] = Wl[i];
    Wrs[i] = Wr[i];
  }
  for (int i = tid; i < H2 * D; i += 256) mW1s[i] = mW1[i];
  if (tid < D) {
    float s = g[tid] * rsqrtf(v[tid] + BN_EPS);
    scale_s[tid] = s;
    shift_s[tid] = (bl[tid] - m[tid]) * s + beta[tid];
  }
  if (tid < H2) {
    mW2s[tid] = mW2[tid];
    mb1s[tid] = mb1[tid];
  }
  __syncthreads();

  int node = blockIdx.x * 256 + tid;
  if (node >= N_NODES) return;

  float acc[D];
#pragma unroll
  for (int d = 0; d < D; ++d) acc[d] = 0.f;

  const uint2* xr = reinterpret_cast<const uint2*>(h1h + (size_t)node * D);
  const uint2* ar = reinterpret_cast<const uint2*>(meanh + (size_t)node * D);

#pragma unroll 1
  for (int kq = 0; kq < D / 4; ++kq) {
    uint2 xu = xr[kq];
    uint2 au = ar[kq];
    float4 xv, av;
    xv.x = bflo(xu.x); xv.y = bfhi(xu.x); xv.z = bflo(xu.y); xv.w = bfhi(xu.y);
    av.x = bflo(au.x); av.y = bfhi(au.x); av.z = bflo(au.y); av.w = bfhi(au.y);
    int k = kq * 4;
#pragma unroll
    for (int d = 0; d < D; ++d) {
      const float4 wl = *reinterpret_cast<const float4*>(&Wls[d * D + k]);
      const float4 wr = *reinterpret_cast<const float4*>(&Wrs[d * D + k]);
      acc[d] += wl.x * av.x + wl.y * av.y + wl.z * av.z + wl.w * av.w
              + wr.x * xv.x + wr.y * xv.y + wr.z * xv.z + wr.w * xv.w;
    }
  }

#pragma unroll
  for (int d = 0; d < D; ++d)
    acc[d] = fmaxf(acc[d] * scale_s[d] + shift_s[d], 0.f);

  float o = mb2[0];
#pragma unroll 1
  for (int j = 0; j < H2; ++j) {
    float zj = mb1s[j];
#pragma unroll
    for (int dq = 0; dq < D / 4; ++dq) {
      const float4 w = *reinterpret_cast<const float4*>(&mW1s[j * D + dq * 4]);
      zj += w.x * acc[dq * 4 + 0] + w.y * acc[dq * 4 + 1]
          + w.z * acc[dq * 4 + 2] + w.w * acc[dq * 4 + 3];
    }
    o += mW2s[j] * fmaxf(zj, 0.f);
  }
  out[node] = 1.0f / (1.0f + expf(-o));
}

// ---------------------------------------------------------------------------
extern "C" void kernel_launch(void* const* d_in, const int* in_sizes, int n_in,
                              void* d_out, int out_size, void* d_ws, size_t ws_size,
                              hipStream_t stream) {
  const float* x    = (const float*)d_in[0];
  const int*   ei   = (const int*)d_in[1];     // [2, E] int32
  const float* Wl1  = (const float*)d_in[2];
  const float* bl1  = (const float*)d_in[3];
  const float* Wr1  = (const float*)d_in[4];
  const float* g1   = (const float*)d_in[5];
  const float* be1  = (const float*)d_in[6];
  const float* m1   = (const float*)d_in[7];
  const float* v1   = (const float*)d_in[8];
  const float* Wl2  = (const float*)d_in[9];
  const float* bl2  = (const float*)d_in[10];
  const float* Wr2  = (const float*)d_in[11];
  const float* g2   = (const float*)d_in[12];
  const float* be2  = (const float*)d_in[13];
  const float* m2   = (const float*)d_in[14];
  const float* v2   = (const float*)d_in[15];
  const float* mW1  = (const float*)d_in[16];
  const float* mb1  = (const float*)d_in[17];
  const float* mW2  = (const float*)d_in[18];
  const float* mb2  = (const float*)d_in[19];
  float* out = (float*)d_out;

  const int* src = ei;
  const int* dst = ei + NE;

  // ws layout (bytes):
  //   meanh : N*D bf16   (12.8 MB)
  //   xh    : N*D bf16   (12.8 MB)
  //   h1h   : N*D bf16   (12.8 MB)
  //   rank  : NE int     ( 4.8 MB)
  //   col   : NE int     ( 4.8 MB)
  //   row_start : N+32 int
  //   bsum  : 256 int
  unsigned short* meanh = (unsigned short*)d_ws;
  unsigned short* xh    = meanh + (size_t)N_NODES * D;
  unsigned short* h1h   = xh + (size_t)N_NODES * D;
  int* rank      = (int*)(h1h + (size_t)N_NODES * D);
  int* col       = rank + NE;
  int* row_start = col + NE;
  int* bsum      = row_start + (N_NODES + 32);

  const int n_scan = N_NODES + 1;
  const int scan_blocks = (n_scan + SCAN_B - 1) / SCAN_B;   // 196
  const int edge_blocks = (NE + 255) / 256;                  // 4688
  const int agg_blocks  = (N_NODES + 3) / 4;                 // 25000
  const int node_blocks = (N_NODES + 255) / 256;             // 391

  // --- CSR build + x->bf16 ---
  hipMemsetAsync(row_start, 0, (size_t)(N_NODES + 1) * sizeof(int), stream);
  prep_kernel<<<edge_blocks, 256, 0, stream>>>(dst, row_start, rank, x, xh);
  scan_part<<<scan_blocks, SCAN_B, 0, stream>>>(row_start, bsum, n_scan);
  scan_mid<<<1, 256, 0, stream>>>(bsum, scan_blocks);
  scan_add<<<scan_blocks, SCAN_B, 0, stream>>>(row_start, bsum, n_scan);
  fill_kernel<<<edge_blocks, 256, 0, stream>>>(src, dst, rank, row_start, col);

  // --- layer 1 ---
  aggregate_kernel<<<agg_blocks, 256, 0, stream>>>(xh, row_start, col, meanh);
  layer1_kernel<<<node_blocks, 256, 0, stream>>>(x, meanh, Wl1, bl1, Wr1,
                                                 g1, be1, m1, v1, h1h);
  // --- layer 2 ---
  aggregate_kernel<<<agg_blocks, 256, 0, stream>>>(h1h, row_start, col, meanh);
  layer2_kernel<<<node_blocks, 256, 0, stream>>>(h1h, meanh, Wl2, bl2, Wr2,
                                                 g2, be2, m2, v2,
                                                 mW1, mb1, mW2, mb2, out);
}

// Round 4
// 386.747 us; speedup vs baseline: 6.0658x; 1.1714x over previous
//
#include <hip/hip_runtime.h>
#include <math.h>

#define N_NODES 100000
#define NE      1200000
#define D       64
#define H2      32
#define BN_EPS  1e-5f
#define SCAN_B  512

typedef short bf16x8 __attribute__((ext_vector_type(8)));
typedef float f32x4 __attribute__((ext_vector_type(4)));

// ---- bf16 helpers (RNE) ----------------------------------------------------
__device__ __forceinline__ unsigned short f2bf(float f) {
  unsigned int u = __float_as_uint(f);
  u += 0x7fffu + ((u >> 16) & 1u);
  return (unsigned short)(u >> 16);
}
__device__ __forceinline__ float bflo(unsigned int u) { return __uint_as_float(u << 16); }
__device__ __forceinline__ float bfhi(unsigned int u) { return __uint_as_float(u & 0xffff0000u); }

// Load 8 consecutive f32 weights, convert to a bf16x8 B-fragment chunk.
__device__ __forceinline__ bf16x8 ldw(const float* p) {
  float4 w0 = *reinterpret_cast<const float4*>(p);
  float4 w1 = *reinterpret_cast<const float4*>(p + 4);
  bf16x8 b;
  b[0] = (short)f2bf(w0.x); b[1] = (short)f2bf(w0.y);
  b[2] = (short)f2bf(w0.z); b[3] = (short)f2bf(w0.w);
  b[4] = (short)f2bf(w1.x); b[5] = (short)f2bf(w1.y);
  b[6] = (short)f2bf(w1.z); b[7] = (short)f2bf(w1.w);
  return b;
}

// ---------------------------------------------------------------------------
// prep: rank+histogram of dst, and x (f32) -> xh (bf16).
// ---------------------------------------------------------------------------
__global__ __launch_bounds__(256) void prep_kernel(
    const int* __restrict__ dst, int* __restrict__ row_start,
    int* __restrict__ rank,
    const float* __restrict__ x, unsigned short* __restrict__ xh) {
  int t = blockIdx.x * 256 + threadIdx.x;
  if (t < NE) rank[t] = atomicAdd(&row_start[1 + dst[t]], 1);
  const int nquads = N_NODES * D / 4;
  const int stride = gridDim.x * 256;
  for (int i = t; i < nquads; i += stride) {
    float4 v = reinterpret_cast<const float4*>(x)[i];
    ushort4 o;
    o.x = f2bf(v.x); o.y = f2bf(v.y); o.z = f2bf(v.z); o.w = f2bf(v.w);
    reinterpret_cast<ushort4*>(xh)[i] = o;
  }
}

// ---------------------------------------------------------------------------
// Blocked scan over row_start[0..N].
// ---------------------------------------------------------------------------
__global__ __launch_bounds__(SCAN_B) void scan_part(int* __restrict__ a,
                                                    int* __restrict__ bsum, int n) {
  __shared__ int s[SCAN_B];
  int i = blockIdx.x * SCAN_B + threadIdx.x;
  int v = (i < n) ? a[i] : 0;
  s[threadIdx.x] = v;
  __syncthreads();
  for (int off = 1; off < SCAN_B; off <<= 1) {
    int t = (threadIdx.x >= off) ? s[threadIdx.x - off] : 0;
    __syncthreads();
    s[threadIdx.x] += t;
    __syncthreads();
  }
  if (i < n) a[i] = s[threadIdx.x];
  if (threadIdx.x == SCAN_B - 1) bsum[blockIdx.x] = s[SCAN_B - 1];
}

__global__ __launch_bounds__(256) void scan_mid(int* __restrict__ bsum, int nb) {
  __shared__ int s[256];
  int v = (threadIdx.x < nb) ? bsum[threadIdx.x] : 0;
  s[threadIdx.x] = v;
  __syncthreads();
  for (int off = 1; off < 256; off <<= 1) {
    int t = (threadIdx.x >= off) ? s[threadIdx.x - off] : 0;
    __syncthreads();
    s[threadIdx.x] += t;
    __syncthreads();
  }
  if (threadIdx.x < nb) bsum[threadIdx.x] = s[threadIdx.x];
}

__global__ __launch_bounds__(SCAN_B) void scan_add(int* __restrict__ a,
                                                   const int* __restrict__ bsum, int n) {
  int i = blockIdx.x * SCAN_B + threadIdx.x;
  if (i >= n || blockIdx.x == 0) return;
  a[i] += bsum[blockIdx.x - 1];
}

// ---------------------------------------------------------------------------
// fill: pure scatter, no atomics.
// ---------------------------------------------------------------------------
__global__ __launch_bounds__(256) void fill_kernel(const int* __restrict__ src,
                                                   const int* __restrict__ dst,
                                                   const int* __restrict__ rank,
                                                   const int* __restrict__ row_start,
                                                   int* __restrict__ col) {
  int e = blockIdx.x * 256 + threadIdx.x;
  if (e >= NE) return;
  col[row_start[dst[e]] + rank[e]] = src[e];
}

// ---------------------------------------------------------------------------
// Gather-aggregate (bf16 rows). One wave per node, paired edges.
// ---------------------------------------------------------------------------
__global__ __launch_bounds__(256) void aggregate_kernel(
    const unsigned short* __restrict__ feat, const int* __restrict__ row_start,
    const int* __restrict__ col, unsigned short* __restrict__ meanout) {
  int w = threadIdx.x >> 6;
  int lane = threadIdx.x & 63;
  int node = blockIdx.x * 4 + w;
  if (node >= N_NODES) return;
  int r0 = row_start[node];
  int r1 = row_start[node + 1];
  int half = lane >> 5;
  int sl = lane & 31;
  float ax = 0.f, ay = 0.f;
  for (int j = r0 + half; j < r1; j += 2) {
    int s = col[j];
    unsigned int u = *reinterpret_cast<const unsigned int*>(feat + s * D + 2 * sl);
    ax += bflo(u);
    ay += bfhi(u);
  }
  ax += __shfl_xor(ax, 32);
  ay += __shfl_xor(ay, 32);
  if (half == 0) {
    float inv = 1.f / fmaxf((float)(r1 - r0), 1.f);
    unsigned int o = (unsigned int)f2bf(ax * inv) | ((unsigned int)f2bf(ay * inv) << 16);
    reinterpret_cast<unsigned int*>(meanout + node * D)[sl] = o;
  }
}

// ---------------------------------------------------------------------------
// Layer 1 via MFMA: h1 = bf16(relu(bn1([mean|x] @ [Wl1;Wr1]^T))).
// Block = 256 thr = 4 waves; wave = 16-node M-tile; 2 M-tiles per wave.
// B-frags (weights, f32->bf16) loaded once, reused across tiles.
// MFMA layouts (gfx950 16x16x32): A: lane l holds A[l%16][8*(l/16)+j];
// B: lane l holds B[8*(l/16)+j][l%16]; D: D[4*(l/16)+r][l%16].
// ---------------------------------------------------------------------------
#define MT 2
__global__ __launch_bounds__(256) void layer1_mfma(
    const unsigned short* __restrict__ meanh, const unsigned short* __restrict__ xh,
    const float* __restrict__ Wl, const float* __restrict__ bl,
    const float* __restrict__ Wr,
    const float* __restrict__ g, const float* __restrict__ beta,
    const float* __restrict__ m, const float* __restrict__ v,
    unsigned short* __restrict__ h1h) {
  __shared__ float scale_s[D];
  __shared__ float shift_s[D];
  int tid = threadIdx.x;
  if (tid < D) {
    float s = g[tid] * rsqrtf(v[tid] + BN_EPS);
    scale_s[tid] = s;
    shift_s[tid] = (bl[tid] - m[tid]) * s + beta[tid];
  }
  __syncthreads();

  int w = tid >> 6, lane = tid & 63, q = lane & 15, kg = lane >> 4;

  // B fragments: K-steps 0,1 from Wl (K=mean), 2,3 from Wr (K=own).
  bf16x8 b[4][4];
#pragma unroll
  for (int f = 0; f < 4; ++f) {
    int c = f * 16 + q;
    b[0][f] = ldw(Wl + c * D + kg * 8);
    b[1][f] = ldw(Wl + c * D + 32 + kg * 8);
    b[2][f] = ldw(Wr + c * D + kg * 8);
    b[3][f] = ldw(Wr + c * D + 32 + kg * 8);
  }

#pragma unroll
  for (int mt = 0; mt < MT; ++mt) {
    int base = blockIdx.x * (64 * MT) + mt * 64 + w * 16;
    int nodeA = base + q;
    if (nodeA > N_NODES - 1) nodeA = N_NODES - 1;
    const unsigned short* mrow = meanh + (size_t)nodeA * D;
    const unsigned short* xrow = xh + (size_t)nodeA * D;
    bf16x8 a0 = *reinterpret_cast<const bf16x8*>(mrow + kg * 8);
    bf16x8 a1 = *reinterpret_cast<const bf16x8*>(mrow + 32 + kg * 8);
    bf16x8 a2 = *reinterpret_cast<const bf16x8*>(xrow + kg * 8);
    bf16x8 a3 = *reinterpret_cast<const bf16x8*>(xrow + 32 + kg * 8);

    f32x4 acc[4];
#pragma unroll
    for (int f = 0; f < 4; ++f) {
      acc[f] = (f32x4){0.f, 0.f, 0.f, 0.f};
      acc[f] = __builtin_amdgcn_mfma_f32_16x16x32_bf16(a0, b[0][f], acc[f], 0, 0, 0);
      acc[f] = __builtin_amdgcn_mfma_f32_16x16x32_bf16(a1, b[1][f], acc[f], 0, 0, 0);
      acc[f] = __builtin_amdgcn_mfma_f32_16x16x32_bf16(a2, b[2][f], acc[f], 0, 0, 0);
      acc[f] = __builtin_amdgcn_mfma_f32_16x16x32_bf16(a3, b[3][f], acc[f], 0, 0, 0);
    }

#pragma unroll
    for (int r = 0; r < 4; ++r) {
      int node_out = base + kg * 4 + r;
      if (node_out < N_NODES) {
#pragma unroll
        for (int f = 0; f < 4; ++f) {
          int c = f * 16 + q;
          float val = fmaxf(acc[f][r] * scale_s[c] + shift_s[c], 0.f);
          h1h[(size_t)node_out * D + c] = f2bf(val);
        }
      }
    }
  }
}

// ---------------------------------------------------------------------------
// Layer 2 via MFMA + MLP head + sigmoid.
// Per M-tile: GEMM -> BN+ReLU -> h2s LDS -> barrier -> head (4 thr/node).
// ---------------------------------------------------------------------------
__global__ __launch_bounds__(256) void layer2_mfma(
    const unsigned short* __restrict__ meanh, const unsigned short* __restrict__ h1h,
    const float* __restrict__ Wl, const float* __restrict__ bl,
    const float* __restrict__ Wr,
    const float* __restrict__ g, const float* __restrict__ beta,
    const float* __restrict__ m, const float* __restrict__ v,
    const float* __restrict__ mW1, const float* __restrict__ mb1,
    const float* __restrict__ mW2, const float* __restrict__ mb2,
    float* __restrict__ out) {
  __shared__ float scale_s[D];
  __shared__ float shift_s[D];
  __shared__ float h2s[64][68];       // [node-in-tile][feature], f32, padded
  __shared__ float mW1s[H2][72];      // padded for b128 reads
  __shared__ float mW2s[H2];
  __shared__ float mb1s[H2];
  int tid = threadIdx.x;
  if (tid < D) {
    float s = g[tid] * rsqrtf(v[tid] + BN_EPS);
    scale_s[tid] = s;
    shift_s[tid] = (bl[tid] - m[tid]) * s + beta[tid];
  }
  for (int i = tid; i < H2 * D; i += 256) mW1s[i >> 6][i & 63] = mW1[i];
  if (tid < H2) {
    mW2s[tid] = mW2[tid];
    mb1s[tid] = mb1[tid];
  }
  __syncthreads();

  int w = tid >> 6, lane = tid & 63, q = lane & 15, kg = lane >> 4;
  int node_h = tid >> 2;   // head: node index in tile
  int qq = tid & 3;        // head: j-quarter
  float mb2v = mb2[0];

  bf16x8 b[4][4];
#pragma unroll
  for (int f = 0; f < 4; ++f) {
    int c = f * 16 + q;
    b[0][f] = ldw(Wl + c * D + kg * 8);
    b[1][f] = ldw(Wl + c * D + 32 + kg * 8);
    b[2][f] = ldw(Wr + c * D + kg * 8);
    b[3][f] = ldw(Wr + c * D + 32 + kg * 8);
  }

#pragma unroll
  for (int mt = 0; mt < MT; ++mt) {
    int tile_base = blockIdx.x * (64 * MT) + mt * 64;
    int base = tile_base + w * 16;
    int nodeA = base + q;
    if (nodeA > N_NODES - 1) nodeA = N_NODES - 1;
    const unsigned short* mrow = meanh + (size_t)nodeA * D;
    const unsigned short* xrow = h1h + (size_t)nodeA * D;
    bf16x8 a0 = *reinterpret_cast<const bf16x8*>(mrow + kg * 8);
    bf16x8 a1 = *reinterpret_cast<const bf16x8*>(mrow + 32 + kg * 8);
    bf16x8 a2 = *reinterpret_cast<const bf16x8*>(xrow + kg * 8);
    bf16x8 a3 = *reinterpret_cast<const bf16x8*>(xrow + 32 + kg * 8);

    f32x4 acc[4];
#pragma unroll
    for (int f = 0; f < 4; ++f) {
      acc[f] = (f32x4){0.f, 0.f, 0.f, 0.f};
      acc[f] = __builtin_amdgcn_mfma_f32_16x16x32_bf16(a0, b[0][f], acc[f], 0, 0, 0);
      acc[f] = __builtin_amdgcn_mfma_f32_16x16x32_bf16(a1, b[1][f], acc[f], 0, 0, 0);
      acc[f] = __builtin_amdgcn_mfma_f32_16x16x32_bf16(a2, b[2][f], acc[f], 0, 0, 0);
      acc[f] = __builtin_amdgcn_mfma_f32_16x16x32_bf16(a3, b[3][f], acc[f], 0, 0, 0);
    }

    // BN + ReLU -> LDS (unguarded: clamped rows hold valid floats)
#pragma unroll
    for (int r = 0; r < 4; ++r) {
#pragma unroll
      for (int f = 0; f < 4; ++f) {
        int c = f * 16 + q;
        h2s[w * 16 + kg * 4 + r][c] = fmaxf(acc[f][r] * scale_s[c] + shift_s[c], 0.f);
      }
    }
    __syncthreads();

    // Head: 4 threads per node, each 8 of 32 hidden units.
    float4 hr[16];
    const float4* h2r = reinterpret_cast<const float4*>(&h2s[node_h][0]);
#pragma unroll
    for (int kq = 0; kq < 16; ++kq) hr[kq] = h2r[kq];
    float o_p = 0.f;
#pragma unroll
    for (int jj = 0; jj < 8; ++jj) {
      int j = qq * 8 + jj;
      float z = mb1s[j];
      const float4* wr4 = reinterpret_cast<const float4*>(&mW1s[j][0]);
#pragma unroll
      for (int kq = 0; kq < 16; ++kq) {
        float4 wv = wr4[kq];
        z += wv.x * hr[kq].x + wv.y * hr[kq].y + wv.z * hr[kq].z + wv.w * hr[kq].w;
      }
      o_p += fmaxf(z, 0.f) * mW2s[j];
    }
    o_p += __shfl_xor(o_p, 1);
    o_p += __shfl_xor(o_p, 2);
    int nodeG = tile_base + node_h;
    if (qq == 0 && nodeG < N_NODES)
      out[nodeG] = 1.0f / (1.0f + expf(-(o_p + mb2v)));
    __syncthreads();
  }
}

// ---------------------------------------------------------------------------
extern "C" void kernel_launch(void* const* d_in, const int* in_sizes, int n_in,
                              void* d_out, int out_size, void* d_ws, size_t ws_size,
                              hipStream_t stream) {
  const float* x    = (const float*)d_in[0];
  const int*   ei   = (const int*)d_in[1];
  const float* Wl1  = (const float*)d_in[2];
  const float* bl1  = (const float*)d_in[3];
  const float* Wr1  = (const float*)d_in[4];
  const float* g1   = (const float*)d_in[5];
  const float* be1  = (const float*)d_in[6];
  const float* m1   = (const float*)d_in[7];
  const float* v1   = (const float*)d_in[8];
  const float* Wl2  = (const float*)d_in[9];
  const float* bl2  = (const float*)d_in[10];
  const float* Wr2  = (const float*)d_in[11];
  const float* g2   = (const float*)d_in[12];
  const float* be2  = (const float*)d_in[13];
  const float* m2   = (const float*)d_in[14];
  const float* v2   = (const float*)d_in[15];
  const float* mW1  = (const float*)d_in[16];
  const float* mb1  = (const float*)d_in[17];
  const float* mW2  = (const float*)d_in[18];
  const float* mb2  = (const float*)d_in[19];
  float* out = (float*)d_out;

  const int* src = ei;
  const int* dst = ei + NE;

  // ws layout: meanh | xh | h1h (bf16, N*D each) | rank | col | row_start | bsum
  unsigned short* meanh = (unsigned short*)d_ws;
  unsigned short* xh    = meanh + (size_t)N_NODES * D;
  unsigned short* h1h   = xh + (size_t)N_NODES * D;
  int* rank      = (int*)(h1h + (size_t)N_NODES * D);
  int* col       = rank + NE;
  int* row_start = col + NE;
  int* bsum      = row_start + (N_NODES + 32);

  const int n_scan = N_NODES + 1;
  const int scan_blocks = (n_scan + SCAN_B - 1) / SCAN_B;
  const int edge_blocks = (NE + 255) / 256;
  const int agg_blocks  = (N_NODES + 3) / 4;
  const int gemm_blocks = (N_NODES + 64 * MT - 1) / (64 * MT);   // 782

  // --- CSR build + x->bf16 ---
  hipMemsetAsync(row_start, 0, (size_t)(N_NODES + 1) * sizeof(int), stream);
  prep_kernel<<<edge_blocks, 256, 0, stream>>>(dst, row_start, rank, x, xh);
  scan_part<<<scan_blocks, SCAN_B, 0, stream>>>(row_start, bsum, n_scan);
  scan_mid<<<1, 256, 0, stream>>>(bsum, scan_blocks);
  scan_add<<<scan_blocks, SCAN_B, 0, stream>>>(row_start, bsum, n_scan);
  fill_kernel<<<edge_blocks, 256, 0, stream>>>(src, dst, rank, row_start, col);

  // --- layer 1 ---
  aggregate_kernel<<<agg_blocks, 256, 0, stream>>>(xh, row_start, col, meanh);
  layer1_mfma<<<gemm_blocks, 256, 0, stream>>>(meanh, xh, Wl1, bl1, Wr1,
                                               g1, be1, m1, v1, h1h);
  // --- layer 2 ---
  aggregate_kernel<<<agg_blocks, 256, 0, stream>>>(h1h, row_start, col, meanh);
  layer2_mfma<<<gemm_blocks, 256, 0, stream>>>(meanh, h1h, Wl2, bl2, Wr2,
                                               g2, be2, m2, v2,
                                               mW1, mb1, mW2, mb2, out);
}

// Round 5
// 327.869 us; speedup vs baseline: 7.1551x; 1.1796x over previous
//
#include <hip/hip_runtime.h>
#include <math.h>

#define N_NODES 100000
#define NE      1200000
#define D       64
#define H2      32
#define BN_EPS  1e-5f
#define SCAN_B  512

typedef short bf16x8 __attribute__((ext_vector_type(8)));
typedef float f32x4 __attribute__((ext_vector_type(4)));

// ---- bf16 helpers (RNE) ----------------------------------------------------
__device__ __forceinline__ unsigned short f2bf(float f) {
  unsigned int u = __float_as_uint(f);
  u += 0x7fffu + ((u >> 16) & 1u);
  return (unsigned short)(u >> 16);
}
__device__ __forceinline__ float bflo(unsigned int u) { return __uint_as_float(u << 16); }
__device__ __forceinline__ float bfhi(unsigned int u) { return __uint_as_float(u & 0xffff0000u); }
__device__ __forceinline__ unsigned int pack2(float lo, float hi) {
  return (unsigned int)f2bf(lo) | ((unsigned int)f2bf(hi) << 16);
}

// Load 8 consecutive f32 weights, convert to a bf16x8 B-fragment chunk.
__device__ __forceinline__ bf16x8 ldw(const float* p) {
  float4 w0 = *reinterpret_cast<const float4*>(p);
  float4 w1 = *reinterpret_cast<const float4*>(p + 4);
  bf16x8 b;
  b[0] = (short)f2bf(w0.x); b[1] = (short)f2bf(w0.y);
  b[2] = (short)f2bf(w0.z); b[3] = (short)f2bf(w0.w);
  b[4] = (short)f2bf(w1.x); b[5] = (short)f2bf(w1.y);
  b[6] = (short)f2bf(w1.z); b[7] = (short)f2bf(w1.w);
  return b;
}

// ---------------------------------------------------------------------------
// prep: rank+histogram of dst, and x (f32) -> xh (bf16).
// ---------------------------------------------------------------------------
__global__ __launch_bounds__(256) void prep_kernel(
    const int* __restrict__ dst, int* __restrict__ row_start,
    int* __restrict__ rank,
    const float* __restrict__ x, unsigned short* __restrict__ xh) {
  int t = blockIdx.x * 256 + threadIdx.x;
  if (t < NE) rank[t] = atomicAdd(&row_start[1 + dst[t]], 1);
  const int nquads = N_NODES * D / 4;
  const int stride = gridDim.x * 256;
  for (int i = t; i < nquads; i += stride) {
    float4 v = reinterpret_cast<const float4*>(x)[i];
    ushort4 o;
    o.x = f2bf(v.x); o.y = f2bf(v.y); o.z = f2bf(v.z); o.w = f2bf(v.w);
    reinterpret_cast<ushort4*>(xh)[i] = o;
  }
}

// ---------------------------------------------------------------------------
// Blocked scan over row_start[0..N].
// ---------------------------------------------------------------------------
__global__ __launch_bounds__(SCAN_B) void scan_part(int* __restrict__ a,
                                                    int* __restrict__ bsum, int n) {
  __shared__ int s[SCAN_B];
  int i = blockIdx.x * SCAN_B + threadIdx.x;
  int v = (i < n) ? a[i] : 0;
  s[threadIdx.x] = v;
  __syncthreads();
  for (int off = 1; off < SCAN_B; off <<= 1) {
    int t = (threadIdx.x >= off) ? s[threadIdx.x - off] : 0;
    __syncthreads();
    s[threadIdx.x] += t;
    __syncthreads();
  }
  if (i < n) a[i] = s[threadIdx.x];
  if (threadIdx.x == SCAN_B - 1) bsum[blockIdx.x] = s[SCAN_B - 1];
}

__global__ __launch_bounds__(256) void scan_mid(int* __restrict__ bsum, int nb) {
  __shared__ int s[256];
  int v = (threadIdx.x < nb) ? bsum[threadIdx.x] : 0;
  s[threadIdx.x] = v;
  __syncthreads();
  for (int off = 1; off < 256; off <<= 1) {
    int t = (threadIdx.x >= off) ? s[threadIdx.x - off] : 0;
    __syncthreads();
    s[threadIdx.x] += t;
    __syncthreads();
  }
  if (threadIdx.x < nb) bsum[threadIdx.x] = s[threadIdx.x];
}

__global__ __launch_bounds__(SCAN_B) void scan_add(int* __restrict__ a,
                                                   const int* __restrict__ bsum, int n) {
  int i = blockIdx.x * SCAN_B + threadIdx.x;
  if (i >= n || blockIdx.x == 0) return;
  a[i] += bsum[blockIdx.x - 1];
}

// ---------------------------------------------------------------------------
// fill: pure scatter, no atomics.
// ---------------------------------------------------------------------------
__global__ __launch_bounds__(256) void fill_kernel(const int* __restrict__ src,
                                                   const int* __restrict__ dst,
                                                   const int* __restrict__ rank,
                                                   const int* __restrict__ row_start,
                                                   int* __restrict__ col) {
  int e = blockIdx.x * 256 + threadIdx.x;
  if (e >= NE) return;
  col[row_start[dst[e]] + rank[e]] = src[e];
}

// ---------------------------------------------------------------------------
// Gather-aggregate v2 (bf16 rows, 128B each).
// Wave = 4 nodes sequentially. Within a node: 16 lanes per edge-row
// (uint2 = 4 bf16 per lane), quarter q handles edges r0+q, r0+q+4, ...,
// 2-deep unrolled so each lane keeps 2 independent gathers in flight.
// Reduce across quarters with shfl_xor(16|32); quarter 0 writes bf16 mean.
// ---------------------------------------------------------------------------
__global__ __launch_bounds__(256) void aggregate_kernel(
    const unsigned short* __restrict__ feat, const int* __restrict__ row_start,
    const int* __restrict__ col, unsigned short* __restrict__ meanout) {
  int w = threadIdx.x >> 6;
  int lane = threadIdx.x & 63;
  int quarter = lane >> 4;
  int sl = lane & 15;
  int nbase = blockIdx.x * 16 + w * 4;
#pragma unroll
  for (int i = 0; i < 4; ++i) {
    int node = nbase + i;
    if (node >= N_NODES) return;   // wave-uniform exit
    int r0 = row_start[node];
    int r1 = row_start[node + 1];
    float a0 = 0.f, a1 = 0.f, a2 = 0.f, a3 = 0.f;
    float c0 = 0.f, c1 = 0.f, c2 = 0.f, c3 = 0.f;
    int j = r0 + quarter;
    for (; j + 4 < r1; j += 8) {
      int s0 = col[j];
      int s1 = col[j + 4];
      uint2 u0 = *reinterpret_cast<const uint2*>(feat + s0 * D + 4 * sl);
      uint2 u1 = *reinterpret_cast<const uint2*>(feat + s1 * D + 4 * sl);
      a0 += bflo(u0.x); a1 += bfhi(u0.x); a2 += bflo(u0.y); a3 += bfhi(u0.y);
      c0 += bflo(u1.x); c1 += bfhi(u1.x); c2 += bflo(u1.y); c3 += bfhi(u1.y);
    }
    if (j < r1) {
      int s0 = col[j];
      uint2 u0 = *reinterpret_cast<const uint2*>(feat + s0 * D + 4 * sl);
      a0 += bflo(u0.x); a1 += bfhi(u0.x); a2 += bflo(u0.y); a3 += bfhi(u0.y);
    }
    a0 += c0; a1 += c1; a2 += c2; a3 += c3;
    a0 += __shfl_xor(a0, 16); a1 += __shfl_xor(a1, 16);
    a2 += __shfl_xor(a2, 16); a3 += __shfl_xor(a3, 16);
    a0 += __shfl_xor(a0, 32); a1 += __shfl_xor(a1, 32);
    a2 += __shfl_xor(a2, 32); a3 += __shfl_xor(a3, 32);
    if (quarter == 0) {
      float inv = 1.f / fmaxf((float)(r1 - r0), 1.f);
      uint2 o;
      o.x = pack2(a0 * inv, a1 * inv);
      o.y = pack2(a2 * inv, a3 * inv);
      *reinterpret_cast<uint2*>(meanout + node * D + 4 * sl) = o;
    }
  }
}

// ---------------------------------------------------------------------------
// Layer 1 via MFMA: h1 = bf16(relu(bn1([mean|x] @ [Wl1;Wr1]^T))).
// ---------------------------------------------------------------------------
#define MT 2
__global__ __launch_bounds__(256) void layer1_mfma(
    const unsigned short* __restrict__ meanh, const unsigned short* __restrict__ xh,
    const float* __restrict__ Wl, const float* __restrict__ bl,
    const float* __restrict__ Wr,
    const float* __restrict__ g, const float* __restrict__ beta,
    const float* __restrict__ m, const float* __restrict__ v,
    unsigned short* __restrict__ h1h) {
  __shared__ float scale_s[D];
  __shared__ float shift_s[D];
  int tid = threadIdx.x;
  if (tid < D) {
    float s = g[tid] * rsqrtf(v[tid] + BN_EPS);
    scale_s[tid] = s;
    shift_s[tid] = (bl[tid] - m[tid]) * s + beta[tid];
  }
  __syncthreads();

  int w = tid >> 6, lane = tid & 63, q = lane & 15, kg = lane >> 4;

  bf16x8 b[4][4];
#pragma unroll
  for (int f = 0; f < 4; ++f) {
    int c = f * 16 + q;
    b[0][f] = ldw(Wl + c * D + kg * 8);
    b[1][f] = ldw(Wl + c * D + 32 + kg * 8);
    b[2][f] = ldw(Wr + c * D + kg * 8);
    b[3][f] = ldw(Wr + c * D + 32 + kg * 8);
  }

#pragma unroll
  for (int mt = 0; mt < MT; ++mt) {
    int base = blockIdx.x * (64 * MT) + mt * 64 + w * 16;
    int nodeA = base + q;
    if (nodeA > N_NODES - 1) nodeA = N_NODES - 1;
    const unsigned short* mrow = meanh + (size_t)nodeA * D;
    const unsigned short* xrow = xh + (size_t)nodeA * D;
    bf16x8 a0 = *reinterpret_cast<const bf16x8*>(mrow + kg * 8);
    bf16x8 a1 = *reinterpret_cast<const bf16x8*>(mrow + 32 + kg * 8);
    bf16x8 a2 = *reinterpret_cast<const bf16x8*>(xrow + kg * 8);
    bf16x8 a3 = *reinterpret_cast<const bf16x8*>(xrow + 32 + kg * 8);

    f32x4 acc[4];
#pragma unroll
    for (int f = 0; f < 4; ++f) {
      acc[f] = (f32x4){0.f, 0.f, 0.f, 0.f};
      acc[f] = __builtin_amdgcn_mfma_f32_16x16x32_bf16(a0, b[0][f], acc[f], 0, 0, 0);
      acc[f] = __builtin_amdgcn_mfma_f32_16x16x32_bf16(a1, b[1][f], acc[f], 0, 0, 0);
      acc[f] = __builtin_amdgcn_mfma_f32_16x16x32_bf16(a2, b[2][f], acc[f], 0, 0, 0);
      acc[f] = __builtin_amdgcn_mfma_f32_16x16x32_bf16(a3, b[3][f], acc[f], 0, 0, 0);
    }

#pragma unroll
    for (int r = 0; r < 4; ++r) {
      int node_out = base + kg * 4 + r;
      if (node_out < N_NODES) {
#pragma unroll
        for (int f = 0; f < 4; ++f) {
          int c = f * 16 + q;
          float val = fmaxf(acc[f][r] * scale_s[c] + shift_s[c], 0.f);
          h1h[(size_t)node_out * D + c] = f2bf(val);
        }
      }
    }
  }
}

// ---------------------------------------------------------------------------
// Layer 2 via MFMA + MLP head + sigmoid.
// ---------------------------------------------------------------------------
__global__ __launch_bounds__(256) void layer2_mfma(
    const unsigned short* __restrict__ meanh, const unsigned short* __restrict__ h1h,
    const float* __restrict__ Wl, const float* __restrict__ bl,
    const float* __restrict__ Wr,
    const float* __restrict__ g, const float* __restrict__ beta,
    const float* __restrict__ m, const float* __restrict__ v,
    const float* __restrict__ mW1, const float* __restrict__ mb1,
    const float* __restrict__ mW2, const float* __restrict__ mb2,
    float* __restrict__ out) {
  __shared__ float scale_s[D];
  __shared__ float shift_s[D];
  __shared__ float h2s[64][68];
  __shared__ float mW1s[H2][72];
  __shared__ float mW2s[H2];
  __shared__ float mb1s[H2];
  int tid = threadIdx.x;
  if (tid < D) {
    float s = g[tid] * rsqrtf(v[tid] + BN_EPS);
    scale_s[tid] = s;
    shift_s[tid] = (bl[tid] - m[tid]) * s + beta[tid];
  }
  for (int i = tid; i < H2 * D; i += 256) mW1s[i >> 6][i & 63] = mW1[i];
  if (tid < H2) {
    mW2s[tid] = mW2[tid];
    mb1s[tid] = mb1[tid];
  }
  __syncthreads();

  int w = tid >> 6, lane = tid & 63, q = lane & 15, kg = lane >> 4;
  int node_h = tid >> 2;
  int qq = tid & 3;
  float mb2v = mb2[0];

  bf16x8 b[4][4];
#pragma unroll
  for (int f = 0; f < 4; ++f) {
    int c = f * 16 + q;
    b[0][f] = ldw(Wl + c * D + kg * 8);
    b[1][f] = ldw(Wl + c * D + 32 + kg * 8);
    b[2][f] = ldw(Wr + c * D + kg * 8);
    b[3][f] = ldw(Wr + c * D + 32 + kg * 8);
  }

#pragma unroll
  for (int mt = 0; mt < MT; ++mt) {
    int tile_base = blockIdx.x * (64 * MT) + mt * 64;
    int base = tile_base + w * 16;
    int nodeA = base + q;
    if (nodeA > N_NODES - 1) nodeA = N_NODES - 1;
    const unsigned short* mrow = meanh + (size_t)nodeA * D;
    const unsigned short* xrow = h1h + (size_t)nodeA * D;
    bf16x8 a0 = *reinterpret_cast<const bf16x8*>(mrow + kg * 8);
    bf16x8 a1 = *reinterpret_cast<const bf16x8*>(mrow + 32 + kg * 8);
    bf16x8 a2 = *reinterpret_cast<const bf16x8*>(xrow + kg * 8);
    bf16x8 a3 = *reinterpret_cast<const bf16x8*>(xrow + 32 + kg * 8);

    f32x4 acc[4];
#pragma unroll
    for (int f = 0; f < 4; ++f) {
      acc[f] = (f32x4){0.f, 0.f, 0.f, 0.f};
      acc[f] = __builtin_amdgcn_mfma_f32_16x16x32_bf16(a0, b[0][f], acc[f], 0, 0, 0);
      acc[f] = __builtin_amdgcn_mfma_f32_16x16x32_bf16(a1, b[1][f], acc[f], 0, 0, 0);
      acc[f] = __builtin_amdgcn_mfma_f32_16x16x32_bf16(a2, b[2][f], acc[f], 0, 0, 0);
      acc[f] = __builtin_amdgcn_mfma_f32_16x16x32_bf16(a3, b[3][f], acc[f], 0, 0, 0);
    }

#pragma unroll
    for (int r = 0; r < 4; ++r) {
#pragma unroll
      for (int f = 0; f < 4; ++f) {
        int c = f * 16 + q;
        h2s[w * 16 + kg * 4 + r][c] = fmaxf(acc[f][r] * scale_s[c] + shift_s[c], 0.f);
      }
    }
    __syncthreads();

    float4 hr[16];
    const float4* h2r = reinterpret_cast<const float4*>(&h2s[node_h][0]);
#pragma unroll
    for (int kq = 0; kq < 16; ++kq) hr[kq] = h2r[kq];
    float o_p = 0.f;
#pragma unroll
    for (int jj = 0; jj < 8; ++jj) {
      int j = qq * 8 + jj;
      float z = mb1s[j];
      const float4* wr4 = reinterpret_cast<const float4*>(&mW1s[j][0]);
#pragma unroll
      for (int kq = 0; kq < 16; ++kq) {
        float4 wv = wr4[kq];
        z += wv.x * hr[kq].x + wv.y * hr[kq].y + wv.z * hr[kq].z + wv.w * hr[kq].w;
      }
      o_p += fmaxf(z, 0.f) * mW2s[j];
    }
    o_p += __shfl_xor(o_p, 1);
    o_p += __shfl_xor(o_p, 2);
    int nodeG = tile_base + node_h;
    if (qq == 0 && nodeG < N_NODES)
      out[nodeG] = 1.0f / (1.0f + expf(-(o_p + mb2v)));
    __syncthreads();
  }
}

// ---------------------------------------------------------------------------
extern "C" void kernel_launch(void* const* d_in, const int* in_sizes, int n_in,
                              void* d_out, int out_size, void* d_ws, size_t ws_size,
                              hipStream_t stream) {
  const float* x    = (const float*)d_in[0];
  const int*   ei   = (const int*)d_in[1];
  const float* Wl1  = (const float*)d_in[2];
  const float* bl1  = (const float*)d_in[3];
  const float* Wr1  = (const float*)d_in[4];
  const float* g1   = (const float*)d_in[5];
  const float* be1  = (const float*)d_in[6];
  const float* m1   = (const float*)d_in[7];
  const float* v1   = (const float*)d_in[8];
  const float* Wl2  = (const float*)d_in[9];
  const float* bl2  = (const float*)d_in[10];
  const float* Wr2  = (const float*)d_in[11];
  const float* g2   = (const float*)d_in[12];
  const float* be2  = (const float*)d_in[13];
  const float* m2   = (const float*)d_in[14];
  const float* v2   = (const float*)d_in[15];
  const float* mW1  = (const float*)d_in[16];
  const float* mb1  = (const float*)d_in[17];
  const float* mW2  = (const float*)d_in[18];
  const float* mb2  = (const float*)d_in[19];
  float* out = (float*)d_out;

  const int* src = ei;
  const int* dst = ei + NE;

  // ws layout: meanh | xh | h1h (bf16, N*D each) | rank | col | row_start | bsum
  unsigned short* meanh = (unsigned short*)d_ws;
  unsigned short* xh    = meanh + (size_t)N_NODES * D;
  unsigned short* h1h   = xh + (size_t)N_NODES * D;
  int* rank      = (int*)(h1h + (size_t)N_NODES * D);
  int* col       = rank + NE;
  int* row_start = col + NE;
  int* bsum      = row_start + (N_NODES + 32);

  const int n_scan = N_NODES + 1;
  const int scan_blocks = (n_scan + SCAN_B - 1) / SCAN_B;
  const int edge_blocks = (NE + 255) / 256;
  const int agg_blocks  = (N_NODES + 15) / 16;               // 6250
  const int gemm_blocks = (N_NODES + 64 * MT - 1) / (64 * MT);

  // --- CSR build + x->bf16 ---
  hipMemsetAsync(row_start, 0, (size_t)(N_NODES + 1) * sizeof(int), stream);
  prep_kernel<<<edge_blocks, 256, 0, stream>>>(dst, row_start, rank, x, xh);
  scan_part<<<scan_blocks, SCAN_B, 0, stream>>>(row_start, bsum, n_scan);
  scan_mid<<<1, 256, 0, stream>>>(bsum, scan_blocks);
  scan_add<<<scan_blocks, SCAN_B, 0, stream>>>(row_start, bsum, n_scan);
  fill_kernel<<<edge_blocks, 256, 0, stream>>>(src, dst, rank, row_start, col);

  // --- layer 1 ---
  aggregate_kernel<<<agg_blocks, 256, 0, stream>>>(xh, row_start, col, meanh);
  layer1_mfma<<<gemm_blocks, 256, 0, stream>>>(meanh, xh, Wl1, bl1, Wr1,
                                               g1, be1, m1, v1, h1h);
  // --- layer 2 ---
  aggregate_kernel<<<agg_blocks, 256, 0, stream>>>(h1h, row_start, col, meanh);
  layer2_mfma<<<gemm_blocks, 256, 0, stream>>>(meanh, h1h, Wl2, bl2, Wr2,
                                               g2, be2, m2, v2,
                                               mW1, mb1, mW2, mb2, out);
}

// Round 6
// 323.700 us; speedup vs baseline: 7.2472x; 1.0129x over previous
//
#include <hip/hip_runtime.h>
#include <math.h>

#define N_NODES 100000
#define NE      1200000
#define D       64
#define H2      32
#define BN_EPS  1e-5f
#define SCAN_B  512
#define NSHARD  8

typedef short bf16x8 __attribute__((ext_vector_type(8)));
typedef float f32x4 __attribute__((ext_vector_type(4)));

// ---- bf16 helpers (RNE) ----------------------------------------------------
__device__ __forceinline__ unsigned short f2bf(float f) {
  unsigned int u = __float_as_uint(f);
  u += 0x7fffu + ((u >> 16) & 1u);
  return (unsigned short)(u >> 16);
}
__device__ __forceinline__ float bflo(unsigned int u) { return __uint_as_float(u << 16); }
__device__ __forceinline__ float bfhi(unsigned int u) { return __uint_as_float(u & 0xffff0000u); }
__device__ __forceinline__ unsigned int pack2(float lo, float hi) {
  return (unsigned int)f2bf(lo) | ((unsigned int)f2bf(hi) << 16);
}

__device__ __forceinline__ bf16x8 ldw(const float* p) {
  float4 w0 = *reinterpret_cast<const float4*>(p);
  float4 w1 = *reinterpret_cast<const float4*>(p + 4);
  bf16x8 b;
  b[0] = (short)f2bf(w0.x); b[1] = (short)f2bf(w0.y);
  b[2] = (short)f2bf(w0.z); b[3] = (short)f2bf(w0.w);
  b[4] = (short)f2bf(w1.x); b[5] = (short)f2bf(w1.y);
  b[6] = (short)f2bf(w1.z); b[7] = (short)f2bf(w1.w);
  return b;
}

// ---------------------------------------------------------------------------
// prep: XCD-sharded rank+histogram of dst, and x (f32) -> xh (bf16).
// Shard = blockIdx & 7: consecutive blocks round-robin XCDs, so each shard's
// atomics stay in one XCD's L2 (no cross-XCD line ping-pong).
// ---------------------------------------------------------------------------
__global__ __launch_bounds__(256) void prep_kernel(
    const int* __restrict__ dst, int* __restrict__ hist8,
    int* __restrict__ rank,
    const float* __restrict__ x, unsigned short* __restrict__ xh) {
  int t = blockIdx.x * 256 + threadIdx.x;
  int shard = blockIdx.x & (NSHARD - 1);
  if (t < NE) rank[t] = atomicAdd(&hist8[shard * N_NODES + dst[t]], 1);
  const int nquads = N_NODES * D / 4;
  const int stride = gridDim.x * 256;
  for (int i = t; i < nquads; i += stride) {
    float4 v = reinterpret_cast<const float4*>(x)[i];
    ushort4 o;
    o.x = f2bf(v.x); o.y = f2bf(v.y); o.z = f2bf(v.z); o.w = f2bf(v.w);
    reinterpret_cast<ushort4*>(xh)[i] = o;
  }
}

// ---------------------------------------------------------------------------
// combine: per node, exclusive-prefix the 8 shard counts in place and emit
// the node's total degree into row_start[1+n].
// ---------------------------------------------------------------------------
__global__ __launch_bounds__(256) void combine_kernel(int* __restrict__ hist8,
                                                      int* __restrict__ row_start) {
  int n = blockIdx.x * 256 + threadIdx.x;
  if (n >= N_NODES) return;
  int run = 0;
#pragma unroll
  for (int s = 0; s < NSHARD; ++s) {
    int c = hist8[s * N_NODES + n];
    hist8[s * N_NODES + n] = run;
    run += c;
  }
  row_start[1 + n] = run;
}

// ---------------------------------------------------------------------------
// Blocked scan over row_start[0..N].
// ---------------------------------------------------------------------------
__global__ __launch_bounds__(SCAN_B) void scan_part(int* __restrict__ a,
                                                    int* __restrict__ bsum, int n) {
  __shared__ int s[SCAN_B];
  int i = blockIdx.x * SCAN_B + threadIdx.x;
  int v = (i < n) ? a[i] : 0;
  s[threadIdx.x] = v;
  __syncthreads();
  for (int off = 1; off < SCAN_B; off <<= 1) {
    int t = (threadIdx.x >= off) ? s[threadIdx.x - off] : 0;
    __syncthreads();
    s[threadIdx.x] += t;
    __syncthreads();
  }
  if (i < n) a[i] = s[threadIdx.x];
  if (threadIdx.x == SCAN_B - 1) bsum[blockIdx.x] = s[SCAN_B - 1];
}

__global__ __launch_bounds__(256) void scan_mid(int* __restrict__ bsum, int nb) {
  __shared__ int s[256];
  int v = (threadIdx.x < nb) ? bsum[threadIdx.x] : 0;
  s[threadIdx.x] = v;
  __syncthreads();
  for (int off = 1; off < 256; off <<= 1) {
    int t = (threadIdx.x >= off) ? s[threadIdx.x - off] : 0;
    __syncthreads();
    s[threadIdx.x] += t;
    __syncthreads();
  }
  if (threadIdx.x < nb) bsum[threadIdx.x] = s[threadIdx.x];
}

__global__ __launch_bounds__(SCAN_B) void scan_add(int* __restrict__ a,
                                                   const int* __restrict__ bsum, int n) {
  int i = blockIdx.x * SCAN_B + threadIdx.x;
  if (i >= n || blockIdx.x == 0) return;
  a[i] += bsum[blockIdx.x - 1];
}

// ---------------------------------------------------------------------------
// fill: pure scatter. Slot = row_start[d] + shard_offset + within-shard rank.
// ---------------------------------------------------------------------------
__global__ __launch_bounds__(256) void fill_kernel(const int* __restrict__ src,
                                                   const int* __restrict__ dst,
                                                   const int* __restrict__ rank,
                                                   const int* __restrict__ row_start,
                                                   const int* __restrict__ hist8,
                                                   int* __restrict__ col) {
  int e = blockIdx.x * 256 + threadIdx.x;
  if (e >= NE) return;
  int shard = blockIdx.x & (NSHARD - 1);
  int d = dst[e];
  col[row_start[d] + hist8[shard * N_NODES + d] + rank[e]] = src[e];
}

// ---------------------------------------------------------------------------
// Gather-aggregate v3 (bf16 rows, 128B each).
// Wave = 4 nodes sequentially; 8 lanes per edge-row (uint4 = 8 bf16/lane);
// oct o covers edges r0+o, r0+o+8, ...; 2-deep unroll -> 16 rows and
// 32B/lane in flight. Reduce across octs with shfl_xor(8|16|32).
// ---------------------------------------------------------------------------
__global__ __launch_bounds__(256) void aggregate_kernel(
    const unsigned short* __restrict__ feat, const int* __restrict__ row_start,
    const int* __restrict__ col, unsigned short* __restrict__ meanout) {
  int w = threadIdx.x >> 6;
  int lane = threadIdx.x & 63;
  int oct = lane >> 3;
  int sl = lane & 7;
  int nbase = blockIdx.x * 16 + w * 4;
#pragma unroll
  for (int i = 0; i < 4; ++i) {
    int node = nbase + i;
    if (node >= N_NODES) return;   // wave-uniform exit
    int r0 = row_start[node];
    int r1 = row_start[node + 1];
    float a0 = 0.f, a1 = 0.f, a2 = 0.f, a3 = 0.f;
    float a4 = 0.f, a5 = 0.f, a6 = 0.f, a7 = 0.f;
    float c0 = 0.f, c1 = 0.f, c2 = 0.f, c3 = 0.f;
    float c4 = 0.f, c5 = 0.f, c6 = 0.f, c7 = 0.f;
    int j = r0 + oct;
    for (; j + 8 < r1; j += 16) {
      int s0 = col[j];
      int s1 = col[j + 8];
      uint4 u0 = *reinterpret_cast<const uint4*>(feat + s0 * D + 8 * sl);
      uint4 u1 = *reinterpret_cast<const uint4*>(feat + s1 * D + 8 * sl);
      a0 += bflo(u0.x); a1 += bfhi(u0.x); a2 += bflo(u0.y); a3 += bfhi(u0.y);
      a4 += bflo(u0.z); a5 += bfhi(u0.z); a6 += bflo(u0.w); a7 += bfhi(u0.w);
      c0 += bflo(u1.x); c1 += bfhi(u1.x); c2 += bflo(u1.y); c3 += bfhi(u1.y);
      c4 += bflo(u1.z); c5 += bfhi(u1.z); c6 += bflo(u1.w); c7 += bfhi(u1.w);
    }
    if (j < r1) {
      int s0 = col[j];
      uint4 u0 = *reinterpret_cast<const uint4*>(feat + s0 * D + 8 * sl);
      a0 += bflo(u0.x); a1 += bfhi(u0.x); a2 += bflo(u0.y); a3 += bfhi(u0.y);
      a4 += bflo(u0.z); a5 += bfhi(u0.z); a6 += bflo(u0.w); a7 += bfhi(u0.w);
    }
    a0 += c0; a1 += c1; a2 += c2; a3 += c3;
    a4 += c4; a5 += c5; a6 += c6; a7 += c7;
#pragma unroll
    for (int d = 8; d <= 32; d <<= 1) {
      a0 += __shfl_xor(a0, d); a1 += __shfl_xor(a1, d);
      a2 += __shfl_xor(a2, d); a3 += __shfl_xor(a3, d);
      a4 += __shfl_xor(a4, d); a5 += __shfl_xor(a5, d);
      a6 += __shfl_xor(a6, d); a7 += __shfl_xor(a7, d);
    }
    if (oct == 0) {
      float inv = 1.f / fmaxf((float)(r1 - r0), 1.f);
      uint4 o;
      o.x = pack2(a0 * inv, a1 * inv);
      o.y = pack2(a2 * inv, a3 * inv);
      o.z = pack2(a4 * inv, a5 * inv);
      o.w = pack2(a6 * inv, a7 * inv);
      *reinterpret_cast<uint4*>(meanout + node * D + 8 * sl) = o;
    }
  }
}

// ---------------------------------------------------------------------------
// Layer 1 via MFMA: h1 = bf16(relu(bn1([mean|x] @ [Wl1;Wr1]^T))).
// ---------------------------------------------------------------------------
#define MT 2
__global__ __launch_bounds__(256) void layer1_mfma(
    const unsigned short* __restrict__ meanh, const unsigned short* __restrict__ xh,
    const float* __restrict__ Wl, const float* __restrict__ bl,
    const float* __restrict__ Wr,
    const float* __restrict__ g, const float* __restrict__ beta,
    const float* __restrict__ m, const float* __restrict__ v,
    unsigned short* __restrict__ h1h) {
  __shared__ float scale_s[D];
  __shared__ float shift_s[D];
  int tid = threadIdx.x;
  if (tid < D) {
    float s = g[tid] * rsqrtf(v[tid] + BN_EPS);
    scale_s[tid] = s;
    shift_s[tid] = (bl[tid] - m[tid]) * s + beta[tid];
  }
  __syncthreads();

  int w = tid >> 6, lane = tid & 63, q = lane & 15, kg = lane >> 4;

  bf16x8 b[4][4];
#pragma unroll
  for (int f = 0; f < 4; ++f) {
    int c = f * 16 + q;
    b[0][f] = ldw(Wl + c * D + kg * 8);
    b[1][f] = ldw(Wl + c * D + 32 + kg * 8);
    b[2][f] = ldw(Wr + c * D + kg * 8);
    b[3][f] = ldw(Wr + c * D + 32 + kg * 8);
  }

#pragma unroll
  for (int mt = 0; mt < MT; ++mt) {
    int base = blockIdx.x * (64 * MT) + mt * 64 + w * 16;
    int nodeA = base + q;
    if (nodeA > N_NODES - 1) nodeA = N_NODES - 1;
    const unsigned short* mrow = meanh + (size_t)nodeA * D;
    const unsigned short* xrow = xh + (size_t)nodeA * D;
    bf16x8 a0 = *reinterpret_cast<const bf16x8*>(mrow + kg * 8);
    bf16x8 a1 = *reinterpret_cast<const bf16x8*>(mrow + 32 + kg * 8);
    bf16x8 a2 = *reinterpret_cast<const bf16x8*>(xrow + kg * 8);
    bf16x8 a3 = *reinterpret_cast<const bf16x8*>(xrow + 32 + kg * 8);

    f32x4 acc[4];
#pragma unroll
    for (int f = 0; f < 4; ++f) {
      acc[f] = (f32x4){0.f, 0.f, 0.f, 0.f};
      acc[f] = __builtin_amdgcn_mfma_f32_16x16x32_bf16(a0, b[0][f], acc[f], 0, 0, 0);
      acc[f] = __builtin_amdgcn_mfma_f32_16x16x32_bf16(a1, b[1][f], acc[f], 0, 0, 0);
      acc[f] = __builtin_amdgcn_mfma_f32_16x16x32_bf16(a2, b[2][f], acc[f], 0, 0, 0);
      acc[f] = __builtin_amdgcn_mfma_f32_16x16x32_bf16(a3, b[3][f], acc[f], 0, 0, 0);
    }

#pragma unroll
    for (int r = 0; r < 4; ++r) {
      int node_out = base + kg * 4 + r;
      if (node_out < N_NODES) {
#pragma unroll
        for (int f = 0; f < 4; ++f) {
          int c = f * 16 + q;
          float val = fmaxf(acc[f][r] * scale_s[c] + shift_s[c], 0.f);
          h1h[(size_t)node_out * D + c] = f2bf(val);
        }
      }
    }
  }
}

// ---------------------------------------------------------------------------
// Layer 2 via MFMA + MLP head + sigmoid.
// ---------------------------------------------------------------------------
__global__ __launch_bounds__(256) void layer2_mfma(
    const unsigned short* __restrict__ meanh, const unsigned short* __restrict__ h1h,
    const float* __restrict__ Wl, const float* __restrict__ bl,
    const float* __restrict__ Wr,
    const float* __restrict__ g, const float* __restrict__ beta,
    const float* __restrict__ m, const float* __restrict__ v,
    const float* __restrict__ mW1, const float* __restrict__ mb1,
    const float* __restrict__ mW2, const float* __restrict__ mb2,
    float* __restrict__ out) {
  __shared__ float scale_s[D];
  __shared__ float shift_s[D];
  __shared__ float h2s[64][68];
  __shared__ float mW1s[H2][72];
  __shared__ float mW2s[H2];
  __shared__ float mb1s[H2];
  int tid = threadIdx.x;
  if (tid < D) {
    float s = g[tid] * rsqrtf(v[tid] + BN_EPS);
    scale_s[tid] = s;
    shift_s[tid] = (bl[tid] - m[tid]) * s + beta[tid];
  }
  for (int i = tid; i < H2 * D; i += 256) mW1s[i >> 6][i & 63] = mW1[i];
  if (tid < H2) {
    mW2s[tid] = mW2[tid];
    mb1s[tid] = mb1[tid];
  }
  __syncthreads();

  int w = tid >> 6, lane = tid & 63, q = lane & 15, kg = lane >> 4;
  int node_h = tid >> 2;
  int qq = tid & 3;
  float mb2v = mb2[0];

  bf16x8 b[4][4];
#pragma unroll
  for (int f = 0; f < 4; ++f) {
    int c = f * 16 + q;
    b[0][f] = ldw(Wl + c * D + kg * 8);
    b[1][f] = ldw(Wl + c * D + 32 + kg * 8);
    b[2][f] = ldw(Wr + c * D + kg * 8);
    b[3][f] = ldw(Wr + c * D + 32 + kg * 8);
  }

#pragma unroll
  for (int mt = 0; mt < MT; ++mt) {
    int tile_base = blockIdx.x * (64 * MT) + mt * 64;
    int base = tile_base + w * 16;
    int nodeA = base + q;
    if (nodeA > N_NODES - 1) nodeA = N_NODES - 1;
    const unsigned short* mrow = meanh + (size_t)nodeA * D;
    const unsigned short* xrow = h1h + (size_t)nodeA * D;
    bf16x8 a0 = *reinterpret_cast<const bf16x8*>(mrow + kg * 8);
    bf16x8 a1 = *reinterpret_cast<const bf16x8*>(mrow + 32 + kg * 8);
    bf16x8 a2 = *reinterpret_cast<const bf16x8*>(xrow + kg * 8);
    bf16x8 a3 = *reinterpret_cast<const bf16x8*>(xrow + 32 + kg * 8);

    f32x4 acc[4];
#pragma unroll
    for (int f = 0; f < 4; ++f) {
      acc[f] = (f32x4){0.f, 0.f, 0.f, 0.f};
      acc[f] = __builtin_amdgcn_mfma_f32_16x16x32_bf16(a0, b[0][f], acc[f], 0, 0, 0);
      acc[f] = __builtin_amdgcn_mfma_f32_16x16x32_bf16(a1, b[1][f], acc[f], 0, 0, 0);
      acc[f] = __builtin_amdgcn_mfma_f32_16x16x32_bf16(a2, b[2][f], acc[f], 0, 0, 0);
      acc[f] = __builtin_amdgcn_mfma_f32_16x16x32_bf16(a3, b[3][f], acc[f], 0, 0, 0);
    }

#pragma unroll
    for (int r = 0; r < 4; ++r) {
#pragma unroll
      for (int f = 0; f < 4; ++f) {
        int c = f * 16 + q;
        h2s[w * 16 + kg * 4 + r][c] = fmaxf(acc[f][r] * scale_s[c] + shift_s[c], 0.f);
      }
    }
    __syncthreads();

    float4 hr[16];
    const float4* h2r = reinterpret_cast<const float4*>(&h2s[node_h][0]);
#pragma unroll
    for (int kq = 0; kq < 16; ++kq) hr[kq] = h2r[kq];
    float o_p = 0.f;
#pragma unroll
    for (int jj = 0; jj < 8; ++jj) {
      int j = qq * 8 + jj;
      float z = mb1s[j];
      const float4* wr4 = reinterpret_cast<const float4*>(&mW1s[j][0]);
#pragma unroll
      for (int kq = 0; kq < 16; ++kq) {
        float4 wv = wr4[kq];
        z += wv.x * hr[kq].x + wv.y * hr[kq].y + wv.z * hr[kq].z + wv.w * hr[kq].w;
      }
      o_p += fmaxf(z, 0.f) * mW2s[j];
    }
    o_p += __shfl_xor(o_p, 1);
    o_p += __shfl_xor(o_p, 2);
    int nodeG = tile_base + node_h;
    if (qq == 0 && nodeG < N_NODES)
      out[nodeG] = 1.0f / (1.0f + expf(-(o_p + mb2v)));
    __syncthreads();
  }
}

// ---------------------------------------------------------------------------
extern "C" void kernel_launch(void* const* d_in, const int* in_sizes, int n_in,
                              void* d_out, int out_size, void* d_ws, size_t ws_size,
                              hipStream_t stream) {
  const float* x    = (const float*)d_in[0];
  const int*   ei   = (const int*)d_in[1];
  const float* Wl1  = (const float*)d_in[2];
  const float* bl1  = (const float*)d_in[3];
  const float* Wr1  = (const float*)d_in[4];
  const float* g1   = (const float*)d_in[5];
  const float* be1  = (const float*)d_in[6];
  const float* m1   = (const float*)d_in[7];
  const float* v1   = (const float*)d_in[8];
  const float* Wl2  = (const float*)d_in[9];
  const float* bl2  = (const float*)d_in[10];
  const float* Wr2  = (const float*)d_in[11];
  const float* g2   = (const float*)d_in[12];
  const float* be2  = (const float*)d_in[13];
  const float* m2   = (const float*)d_in[14];
  const float* v2   = (const float*)d_in[15];
  const float* mW1  = (const float*)d_in[16];
  const float* mb1  = (const float*)d_in[17];
  const float* mW2  = (const float*)d_in[18];
  const float* mb2  = (const float*)d_in[19];
  float* out = (float*)d_out;

  const int* src = ei;
  const int* dst = ei + NE;

  // ws layout: meanh | xh | h1h (bf16, N*D each) | rank | col |
  //            row_start (N+1, padded to 100016) | hist8 (8N) | bsum
  unsigned short* meanh = (unsigned short*)d_ws;
  unsigned short* xh    = meanh + (size_t)N_NODES * D;
  unsigned short* h1h   = xh + (size_t)N_NODES * D;
  int* rank      = (int*)(h1h + (size_t)N_NODES * D);
  int* col       = rank + NE;
  int* row_start = col + NE;
  int* hist8     = row_start + 100016;
  int* bsum      = hist8 + NSHARD * N_NODES;

  const int n_scan = N_NODES + 1;
  const int scan_blocks = (n_scan + SCAN_B - 1) / SCAN_B;
  const int edge_blocks = (NE + 255) / 256;
  const int node256     = (N_NODES + 255) / 256;
  const int agg_blocks  = (N_NODES + 15) / 16;
  const int gemm_blocks = (N_NODES + 64 * MT - 1) / (64 * MT);

  // --- CSR build + x->bf16 ---
  hipMemsetAsync(row_start, 0, (size_t)(100016 + NSHARD * N_NODES) * sizeof(int), stream);
  prep_kernel<<<edge_blocks, 256, 0, stream>>>(dst, hist8, rank, x, xh);
  combine_kernel<<<node256, 256, 0, stream>>>(hist8, row_start);
  scan_part<<<scan_blocks, SCAN_B, 0, stream>>>(row_start, bsum, n_scan);
  scan_mid<<<1, 256, 0, stream>>>(bsum, scan_blocks);
  scan_add<<<scan_blocks, SCAN_B, 0, stream>>>(row_start, bsum, n_scan);
  fill_kernel<<<edge_blocks, 256, 0, stream>>>(src, dst, rank, row_start, hist8, col);

  // --- layer 1 ---
  aggregate_kernel<<<agg_blocks, 256, 0, stream>>>(xh, row_start, col, meanh);
  layer1_mfma<<<gemm_blocks, 256, 0, stream>>>(meanh, xh, Wl1, bl1, Wr1,
                                               g1, be1, m1, v1, h1h);
  // --- layer 2 ---
  aggregate_kernel<<<agg_blocks, 256, 0, stream>>>(h1h, row_start, col, meanh);
  layer2_mfma<<<gemm_blocks, 256, 0, stream>>>(meanh, h1h, Wl2, bl2, Wr2,
                                               g2, be2, m2, v2,
                                               mW1, mb1, mW2, mb2, out);
}

// Round 8
// 285.463 us; speedup vs baseline: 8.2180x; 1.1339x over previous
//
#include <hip/hip_runtime.h>
#include <math.h>

#define N_NODES 100000
#define NE      1200000
#define D       64
#define H2      32
#define BN_EPS  1e-5f
#define SCAN_B  512

// bucket sort parameters
#define BSHIFT  9
#define BNODES  512                      // nodes per coarse bucket
#define NBUK    256                      // bucket slots (used: 196)
#define NBUK_USED ((N_NODES + BNODES - 1) / BNODES)   // 196
#define NB1     512                      // pass-1 blocks
#define EPB1    ((NE + NB1 - 1) / NB1)   // 2344 edges per pass-1 block
#define NSCAN   (NBUK * NB1)             // 131072 scan entries
#define SRC_BITS 17
#define SRC_MASK ((1 << SRC_BITS) - 1)

typedef short bf16x8 __attribute__((ext_vector_type(8)));
typedef float f32x4 __attribute__((ext_vector_type(4)));

// ---- bf16 helpers (RNE) ----------------------------------------------------
__device__ __forceinline__ unsigned short f2bf(float f) {
  unsigned int u = __float_as_uint(f);
  u += 0x7fffu + ((u >> 16) & 1u);
  return (unsigned short)(u >> 16);
}
__device__ __forceinline__ float bflo(unsigned int u) { return __uint_as_float(u << 16); }
__device__ __forceinline__ float bfhi(unsigned int u) { return __uint_as_float(u & 0xffff0000u); }
__device__ __forceinline__ unsigned int pack2(float lo, float hi) {
  return (unsigned int)f2bf(lo) | ((unsigned int)f2bf(hi) << 16);
}

__device__ __forceinline__ bf16x8 ldw(const float* p) {
  float4 w0 = *reinterpret_cast<const float4*>(p);
  float4 w1 = *reinterpret_cast<const float4*>(p + 4);
  bf16x8 b;
  b[0] = (short)f2bf(w0.x); b[1] = (short)f2bf(w0.y);
  b[2] = (short)f2bf(w0.z); b[3] = (short)f2bf(w0.w);
  b[4] = (short)f2bf(w1.x); b[5] = (short)f2bf(w1.y);
  b[6] = (short)f2bf(w1.z); b[7] = (short)f2bf(w1.w);
  return b;
}

// ---------------------------------------------------------------------------
// Pass 1a: per-block LDS histogram of coarse buckets (dst>>9); also converts
// x (f32) -> xh (bf16). All atomics are LDS (no fabric traffic).
// ---------------------------------------------------------------------------
__global__ __launch_bounds__(256) void bucket_hist_kernel(
    const int* __restrict__ dst, int* __restrict__ bhist,
    const float* __restrict__ x, unsigned short* __restrict__ xh) {
  __shared__ int h[NBUK];
  int tid = threadIdx.x;
  h[tid] = 0;
  __syncthreads();
  int e0 = blockIdx.x * EPB1;
  int e1 = e0 + EPB1; if (e1 > NE) e1 = NE;
  for (int e = e0 + tid; e < e1; e += 256)
    atomicAdd(&h[dst[e] >> BSHIFT], 1);
  __syncthreads();
  bhist[tid * NB1 + blockIdx.x] = h[tid];

  // x -> bf16 (grid-stride)
  const int nquads = N_NODES * D / 4;
  for (int i = blockIdx.x * 256 + tid; i < nquads; i += NB1 * 256) {
    float4 v = reinterpret_cast<const float4*>(x)[i];
    ushort4 o;
    o.x = f2bf(v.x); o.y = f2bf(v.y); o.z = f2bf(v.z); o.w = f2bf(v.w);
    reinterpret_cast<ushort4*>(xh)[i] = o;
  }
}

// ---------------------------------------------------------------------------
// Blocked inclusive scan over bhist[0..NSCAN).
// ---------------------------------------------------------------------------
__global__ __launch_bounds__(SCAN_B) void scan_part(int* __restrict__ a,
                                                    int* __restrict__ bsum, int n) {
  __shared__ int s[SCAN_B];
  int i = blockIdx.x * SCAN_B + threadIdx.x;
  int v = (i < n) ? a[i] : 0;
  s[threadIdx.x] = v;
  __syncthreads();
  for (int off = 1; off < SCAN_B; off <<= 1) {
    int t = (threadIdx.x >= off) ? s[threadIdx.x - off] : 0;
    __syncthreads();
    s[threadIdx.x] += t;
    __syncthreads();
  }
  if (i < n) a[i] = s[threadIdx.x];
  if (threadIdx.x == SCAN_B - 1) bsum[blockIdx.x] = s[SCAN_B - 1];
}

__global__ __launch_bounds__(256) void scan_mid(int* __restrict__ bsum, int nb) {
  __shared__ int s[256];
  int v = (threadIdx.x < nb) ? bsum[threadIdx.x] : 0;
  s[threadIdx.x] = v;
  __syncthreads();
  for (int off = 1; off < 256; off <<= 1) {
    int t = (threadIdx.x >= off) ? s[threadIdx.x - off] : 0;
    __syncthreads();
    s[threadIdx.x] += t;
    __syncthreads();
  }
  if (threadIdx.x < nb) bsum[threadIdx.x] = s[threadIdx.x];
}

__global__ __launch_bounds__(SCAN_B) void scan_add(int* __restrict__ a,
                                                   const int* __restrict__ bsum, int n) {
  int i = blockIdx.x * SCAN_B + threadIdx.x;
  if (i >= n || blockIdx.x == 0) return;
  a[i] += bsum[blockIdx.x - 1];
}

// ---------------------------------------------------------------------------
// Pass 1b: scatter packed edges into bucket-grouped ebuk via LDS cursors.
// packed = (dst & 511) << 17 | src  (src < 2^17, local dst < 2^9).
// Region base for (bucket b, block blk) = scanned[b*NB1+blk - 1] (0 at idx 0).
// ---------------------------------------------------------------------------
__global__ __launch_bounds__(256) void bucket_scatter_kernel(
    const int* __restrict__ src, const int* __restrict__ dst,
    const int* __restrict__ scanned, int* __restrict__ ebuk) {
  __shared__ int cur[NBUK];
  int tid = threadIdx.x;
  int idx = tid * NB1 + blockIdx.x;
  cur[tid] = (idx == 0) ? 0 : scanned[idx - 1];
  __syncthreads();
  int e0 = blockIdx.x * EPB1;
  int e1 = e0 + EPB1; if (e1 > NE) e1 = NE;
  for (int e = e0 + tid; e < e1; e += 256) {
    int d = dst[e];
    int pos = atomicAdd(&cur[d >> BSHIFT], 1);
    ebuk[pos] = ((d & (BNODES - 1)) << SRC_BITS) | src[e];
  }
}

// ---------------------------------------------------------------------------
// Pass 2: one block per coarse bucket. Exact per-node LDS histogram ->
// LDS scan -> coalesced row_start write -> LDS-cursor scatter of col.
// Bucket edge region ~24KB (L2-resident); all atomics LDS.
// ---------------------------------------------------------------------------
__global__ __launch_bounds__(512) void bucket_csr_kernel(
    const int* __restrict__ ebuk, const int* __restrict__ scanned,
    int* __restrict__ row_start, int* __restrict__ col) {
  __shared__ int h[BNODES];
  __shared__ int cur[BNODES];
  int b = blockIdx.x;
  int tid = threadIdx.x;
  int base = (b == 0) ? 0 : scanned[b * NB1 - 1];
  int end  = scanned[(b + 1) * NB1 - 1];
  h[tid] = 0;
  __syncthreads();
  for (int p = base + tid; p < end; p += 512)
    atomicAdd(&h[ebuk[p] >> SRC_BITS], 1);
  __syncthreads();
  int orig = h[tid];
  for (int off = 1; off < 512; off <<= 1) {
    int t = (tid >= off) ? h[tid - off] : 0;
    __syncthreads();
    h[tid] += t;
    __syncthreads();
  }
  int excl = h[tid] - orig;
  int n = (b << BSHIFT) + tid;
  if (n < N_NODES) row_start[n] = base + excl;
  if (b == NBUK_USED - 1 && tid == 0) row_start[N_NODES] = end;
  cur[tid] = base + excl;
  __syncthreads();
  for (int p = base + tid; p < end; p += 512) {
    int packed = ebuk[p];
    int pos = atomicAdd(&cur[packed >> SRC_BITS], 1);
    col[pos] = packed & SRC_MASK;
  }
}

// ---------------------------------------------------------------------------
// Gather-aggregate v3 (bf16 rows, 128B each). Wave = 4 nodes sequentially;
// 8 lanes per edge-row (uint4 = 8 bf16/lane); 2-deep unroll.
// ---------------------------------------------------------------------------
__global__ __launch_bounds__(256) void aggregate_kernel(
    const unsigned short* __restrict__ feat, const int* __restrict__ row_start,
    const int* __restrict__ col, unsigned short* __restrict__ meanout) {
  int w = threadIdx.x >> 6;
  int lane = threadIdx.x & 63;
  int oct = lane >> 3;
  int sl = lane & 7;
  int nbase = blockIdx.x * 16 + w * 4;
#pragma unroll
  for (int i = 0; i < 4; ++i) {
    int node = nbase + i;
    if (node >= N_NODES) return;   // wave-uniform exit
    int r0 = row_start[node];
    int r1 = row_start[node + 1];
    float a0 = 0.f, a1 = 0.f, a2 = 0.f, a3 = 0.f;
    float a4 = 0.f, a5 = 0.f, a6 = 0.f, a7 = 0.f;
    float c0 = 0.f, c1 = 0.f, c2 = 0.f, c3 = 0.f;
    float c4 = 0.f, c5 = 0.f, c6 = 0.f, c7 = 0.f;
    int j = r0 + oct;
    for (; j + 8 < r1; j += 16) {
      int s0 = col[j];
      int s1 = col[j + 8];
      uint4 u0 = *reinterpret_cast<const uint4*>(feat + s0 * D + 8 * sl);
      uint4 u1 = *reinterpret_cast<const uint4*>(feat + s1 * D + 8 * sl);
      a0 += bflo(u0.x); a1 += bfhi(u0.x); a2 += bflo(u0.y); a3 += bfhi(u0.y);
      a4 += bflo(u0.z); a5 += bfhi(u0.z); a6 += bflo(u0.w); a7 += bfhi(u0.w);
      c0 += bflo(u1.x); c1 += bfhi(u1.x); c2 += bflo(u1.y); c3 += bfhi(u1.y);
      c4 += bflo(u1.z); c5 += bfhi(u1.z); c6 += bflo(u1.w); c7 += bfhi(u1.w);
    }
    if (j < r1) {
      int s0 = col[j];
      uint4 u0 = *reinterpret_cast<const uint4*>(feat + s0 * D + 8 * sl);
      a0 += bflo(u0.x); a1 += bfhi(u0.x); a2 += bflo(u0.y); a3 += bfhi(u0.y);
      a4 += bflo(u0.z); a5 += bfhi(u0.z); a6 += bflo(u0.w); a7 += bfhi(u0.w);
    }
    a0 += c0; a1 += c1; a2 += c2; a3 += c3;
    a4 += c4; a5 += c5; a6 += c6; a7 += c7;
#pragma unroll
    for (int d = 8; d <= 32; d <<= 1) {
      a0 += __shfl_xor(a0, d); a1 += __shfl_xor(a1, d);
      a2 += __shfl_xor(a2, d); a3 += __shfl_xor(a3, d);
      a4 += __shfl_xor(a4, d); a5 += __shfl_xor(a5, d);
      a6 += __shfl_xor(a6, d); a7 += __shfl_xor(a7, d);
    }
    if (oct == 0) {
      float inv = 1.f / fmaxf((float)(r1 - r0), 1.f);
      uint4 o;
      o.x = pack2(a0 * inv, a1 * inv);
      o.y = pack2(a2 * inv, a3 * inv);
      o.z = pack2(a4 * inv, a5 * inv);
      o.w = pack2(a6 * inv, a7 * inv);
      *reinterpret_cast<uint4*>(meanout + node * D + 8 * sl) = o;
    }
  }
}

// ---------------------------------------------------------------------------
// Layer 1 via MFMA: h1 = bf16(relu(bn1([mean|x] @ [Wl1;Wr1]^T))).
// ---------------------------------------------------------------------------
#define MT 2
__global__ __launch_bounds__(256) void layer1_mfma(
    const unsigned short* __restrict__ meanh, const unsigned short* __restrict__ xh,
    const float* __restrict__ Wl, const float* __restrict__ bl,
    const float* __restrict__ Wr,
    const float* __restrict__ g, const float* __restrict__ beta,
    const float* __restrict__ m, const float* __restrict__ v,
    unsigned short* __restrict__ h1h) {
  __shared__ float scale_s[D];
  __shared__ float shift_s[D];
  int tid = threadIdx.x;
  if (tid < D) {
    float s = g[tid] * rsqrtf(v[tid] + BN_EPS);
    scale_s[tid] = s;
    shift_s[tid] = (bl[tid] - m[tid]) * s + beta[tid];
  }
  __syncthreads();

  int w = tid >> 6, lane = tid & 63, q = lane & 15, kg = lane >> 4;

  bf16x8 b[4][4];
#pragma unroll
  for (int f = 0; f < 4; ++f) {
    int c = f * 16 + q;
    b[0][f] = ldw(Wl + c * D + kg * 8);
    b[1][f] = ldw(Wl + c * D + 32 + kg * 8);
    b[2][f] = ldw(Wr + c * D + kg * 8);
    b[3][f] = ldw(Wr + c * D + 32 + kg * 8);
  }

#pragma unroll
  for (int mt = 0; mt < MT; ++mt) {
    int base = blockIdx.x * (64 * MT) + mt * 64 + w * 16;
    int nodeA = base + q;
    if (nodeA > N_NODES - 1) nodeA = N_NODES - 1;
    const unsigned short* mrow = meanh + (size_t)nodeA * D;
    const unsigned short* xrow = xh + (size_t)nodeA * D;
    bf16x8 a0 = *reinterpret_cast<const bf16x8*>(mrow + kg * 8);
    bf16x8 a1 = *reinterpret_cast<const bf16x8*>(mrow + 32 + kg * 8);
    bf16x8 a2 = *reinterpret_cast<const bf16x8*>(xrow + kg * 8);
    bf16x8 a3 = *reinterpret_cast<const bf16x8*>(xrow + 32 + kg * 8);

    f32x4 acc[4];
#pragma unroll
    for (int f = 0; f < 4; ++f) {
      acc[f] = (f32x4){0.f, 0.f, 0.f, 0.f};
      acc[f] = __builtin_amdgcn_mfma_f32_16x16x32_bf16(a0, b[0][f], acc[f], 0, 0, 0);
      acc[f] = __builtin_amdgcn_mfma_f32_16x16x32_bf16(a1, b[1][f], acc[f], 0, 0, 0);
      acc[f] = __builtin_amdgcn_mfma_f32_16x16x32_bf16(a2, b[2][f], acc[f], 0, 0, 0);
      acc[f] = __builtin_amdgcn_mfma_f32_16x16x32_bf16(a3, b[3][f], acc[f], 0, 0, 0);
    }

#pragma unroll
    for (int r = 0; r < 4; ++r) {
      int node_out = base + kg * 4 + r;
      if (node_out < N_NODES) {
#pragma unroll
        for (int f = 0; f < 4; ++f) {
          int c = f * 16 + q;
          float val = fmaxf(acc[f][r] * scale_s[c] + shift_s[c], 0.f);
          h1h[(size_t)node_out * D + c] = f2bf(val);
        }
      }
    }
  }
}

// ---------------------------------------------------------------------------
// Layer 2 via MFMA + MLP head + sigmoid.
// ---------------------------------------------------------------------------
__global__ __launch_bounds__(256) void layer2_mfma(
    const unsigned short* __restrict__ meanh, const unsigned short* __restrict__ h1h,
    const float* __restrict__ Wl, const float* __restrict__ bl,
    const float* __restrict__ Wr,
    const float* __restrict__ g, const float* __restrict__ beta,
    const float* __restrict__ m, const float* __restrict__ v,
    const float* __restrict__ mW1, const float* __restrict__ mb1,
    const float* __restrict__ mW2, const float* __restrict__ mb2,
    float* __restrict__ out) {
  __shared__ float scale_s[D];
  __shared__ float shift_s[D];
  __shared__ float h2s[64][68];
  __shared__ float mW1s[H2][72];
  __shared__ float mW2s[H2];
  __shared__ float mb1s[H2];
  int tid = threadIdx.x;
  if (tid < D) {
    float s = g[tid] * rsqrtf(v[tid] + BN_EPS);
    scale_s[tid] = s;
    shift_s[tid] = (bl[tid] - m[tid]) * s + beta[tid];
  }
  for (int i = tid; i < H2 * D; i += 256) mW1s[i >> 6][i & 63] = mW1[i];
  if (tid < H2) {
    mW2s[tid] = mW2[tid];
    mb1s[tid] = mb1[tid];
  }
  __syncthreads();

  int w = tid >> 6, lane = tid & 63, q = lane & 15, kg = lane >> 4;
  int node_h = tid >> 2;
  int qq = tid & 3;
  float mb2v = mb2[0];

  bf16x8 b[4][4];
#pragma unroll
  for (int f = 0; f < 4; ++f) {
    int c = f * 16 + q;
    b[0][f] = ldw(Wl + c * D + kg * 8);
    b[1][f] = ldw(Wl + c * D + 32 + kg * 8);
    b[2][f] = ldw(Wr + c * D + kg * 8);
    b[3][f] = ldw(Wr + c * D + 32 + kg * 8);
  }

#pragma unroll
  for (int mt = 0; mt < MT; ++mt) {
    int tile_base = blockIdx.x * (64 * MT) + mt * 64;
    int base = tile_base + w * 16;
    int nodeA = base + q;
    if (nodeA > N_NODES - 1) nodeA = N_NODES - 1;
    const unsigned short* mrow = meanh + (size_t)nodeA * D;
    const unsigned short* xrow = h1h + (size_t)nodeA * D;
    bf16x8 a0 = *reinterpret_cast<const bf16x8*>(mrow + kg * 8);
    bf16x8 a1 = *reinterpret_cast<const bf16x8*>(mrow + 32 + kg * 8);
    bf16x8 a2 = *reinterpret_cast<const bf16x8*>(xrow + kg * 8);
    bf16x8 a3 = *reinterpret_cast<const bf16x8*>(xrow + 32 + kg * 8);

    f32x4 acc[4];
#pragma unroll
    for (int f = 0; f < 4; ++f) {
      acc[f] = (f32x4){0.f, 0.f, 0.f, 0.f};
      acc[f] = __builtin_amdgcn_mfma_f32_16x16x32_bf16(a0, b[0][f], acc[f], 0, 0, 0);
      acc[f] = __builtin_amdgcn_mfma_f32_16x16x32_bf16(a1, b[1][f], acc[f], 0, 0, 0);
      acc[f] = __builtin_amdgcn_mfma_f32_16x16x32_bf16(a2, b[2][f], acc[f], 0, 0, 0);
      acc[f] = __builtin_amdgcn_mfma_f32_16x16x32_bf16(a3, b[3][f], acc[f], 0, 0, 0);
    }

#pragma unroll
    for (int r = 0; r < 4; ++r) {
#pragma unroll
      for (int f = 0; f < 4; ++f) {
        int c = f * 16 + q;
        h2s[w * 16 + kg * 4 + r][c] = fmaxf(acc[f][r] * scale_s[c] + shift_s[c], 0.f);
      }
    }
    __syncthreads();

    float4 hr[16];
    const float4* h2r = reinterpret_cast<const float4*>(&h2s[node_h][0]);
#pragma unroll
    for (int kq = 0; kq < 16; ++kq) hr[kq] = h2r[kq];
    float o_p = 0.f;
#pragma unroll
    for (int jj = 0; jj < 8; ++jj) {
      int j = qq * 8 + jj;
      float z = mb1s[j];
      const float4* wr4 = reinterpret_cast<const float4*>(&mW1s[j][0]);
#pragma unroll
      for (int kq = 0; kq < 16; ++kq) {
        float4 wv = wr4[kq];
        z += wv.x * hr[kq].x + wv.y * hr[kq].y + wv.z * hr[kq].z + wv.w * hr[kq].w;
      }
      o_p += fmaxf(z, 0.f) * mW2s[j];
    }
    o_p += __shfl_xor(o_p, 1);
    o_p += __shfl_xor(o_p, 2);
    int nodeG = tile_base + node_h;
    if (qq == 0 && nodeG < N_NODES)
      out[nodeG] = 1.0f / (1.0f + expf(-(o_p + mb2v)));
    __syncthreads();
  }
}

// ---------------------------------------------------------------------------
extern "C" void kernel_launch(void* const* d_in, const int* in_sizes, int n_in,
                              void* d_out, int out_size, void* d_ws, size_t ws_size,
                              hipStream_t stream) {
  const float* x    = (const float*)d_in[0];
  const int*   ei   = (const int*)d_in[1];
  const float* Wl1  = (const float*)d_in[2];
  const float* bl1  = (const float*)d_in[3];
  const float* Wr1  = (const float*)d_in[4];
  const float* g1   = (const float*)d_in[5];
  const float* be1  = (const float*)d_in[6];
  const float* m1   = (const float*)d_in[7];
  const float* v1   = (const float*)d_in[8];
  const float* Wl2  = (const float*)d_in[9];
  const float* bl2  = (const float*)d_in[10];
  const float* Wr2  = (const float*)d_in[11];
  const float* g2   = (const float*)d_in[12];
  const float* be2  = (const float*)d_in[13];
  const float* m2   = (const float*)d_in[14];
  const float* v2   = (const float*)d_in[15];
  const float* mW1  = (const float*)d_in[16];
  const float* mb1  = (const float*)d_in[17];
  const float* mW2  = (const float*)d_in[18];
  const float* mb2  = (const float*)d_in[19];
  float* out = (float*)d_out;

  const int* src = ei;
  const int* dst = ei + NE;

  // ws layout (no memsets; everything written before read):
  //   meanh : N*D bf16 (12.8MB)
  //   xh    : N*D bf16
  //   h1h   : N*D bf16
  //   ebuk  : NE int   (4.8MB, packed (dst&511)<<17|src)
  //   col   : NE int
  //   row_start : N+16 int
  //   bhist : NSCAN int (512KB)
  //   bsum  : 512 int
  unsigned short* meanh = (unsigned short*)d_ws;
  unsigned short* xh    = meanh + (size_t)N_NODES * D;
  unsigned short* h1h   = xh + (size_t)N_NODES * D;
  int* ebuk      = (int*)(h1h + (size_t)N_NODES * D);
  int* col       = ebuk + NE;
  int* row_start = col + NE;
  int* bhist     = row_start + (N_NODES + 16);
  int* bsum      = bhist + NSCAN;

  const int scan_blocks = NSCAN / SCAN_B;                    // 256
  const int agg_blocks  = (N_NODES + 15) / 16;
  const int gemm_blocks = (N_NODES + 64 * MT - 1) / (64 * MT);

  // --- CSR build (LDS bucket counting sort, zero global atomics) ---
  bucket_hist_kernel<<<NB1, 256, 0, stream>>>(dst, bhist, x, xh);
  scan_part<<<scan_blocks, SCAN_B, 0, stream>>>(bhist, bsum, NSCAN);
  scan_mid<<<1, 256, 0, stream>>>(bsum, scan_blocks);
  scan_add<<<scan_blocks, SCAN_B, 0, stream>>>(bhist, bsum, NSCAN);
  bucket_scatter_kernel<<<NB1, 256, 0, stream>>>(src, dst, bhist, ebuk);
  bucket_csr_kernel<<<NBUK_USED, 512, 0, stream>>>(ebuk, bhist, row_start, col);

  // --- layer 1 ---
  aggregate_kernel<<<agg_blocks, 256, 0, stream>>>(xh, row_start, col, meanh);
  layer1_mfma<<<gemm_blocks, 256, 0, stream>>>(meanh, xh, Wl1, bl1, Wr1,
                                               g1, be1, m1, v1, h1h);
  // --- layer 2 ---
  aggregate_kernel<<<agg_blocks, 256, 0, stream>>>(h1h, row_start, col, meanh);
  layer2_mfma<<<gemm_blocks, 256, 0, stream>>>(meanh, h1h, Wl2, bl2, Wr2,
                                               g2, be2, m2, v2,
                                               mW1, mb1, mW2, mb2, out);
}

// Round 10
// 272.183 us; speedup vs baseline: 8.6189x; 1.0488x over previous
//
#include <hip/hip_runtime.h>
#include <math.h>

#define N_NODES 100000
#define NE      1200000
#define D       64
#define H2      32
#define BN_EPS  1e-5f
#define SCAN_B  512

// bucket sort parameters
#define BSHIFT  9
#define BNODES  512                      // nodes per coarse bucket
#define NBUK    256                      // bucket slots (used: 196)
#define NBUK_USED ((N_NODES + BNODES - 1) / BNODES)   // 196
#define NB1     512                      // pass-1 blocks
#define EPB1    ((NE + NB1 - 1) / NB1)   // 2344 edges per pass-1 block
#define NSCAN   (NBUK * NB1)             // 131072 scan entries
#define SRC_BITS 17
#define SRC_MASK ((1 << SRC_BITS) - 1)

typedef short bf16x8 __attribute__((ext_vector_type(8)));
typedef float f32x4 __attribute__((ext_vector_type(4)));

// ---- bf16 helpers (RNE) ----------------------------------------------------
__device__ __forceinline__ unsigned short f2bf(float f) {
  unsigned int u = __float_as_uint(f);
  u += 0x7fffu + ((u >> 16) & 1u);
  return (unsigned short)(u >> 16);
}
__device__ __forceinline__ float bflo(unsigned int u) { return __uint_as_float(u << 16); }
__device__ __forceinline__ float bfhi(unsigned int u) { return __uint_as_float(u & 0xffff0000u); }
__device__ __forceinline__ unsigned int pack2(float lo, float hi) {
  return (unsigned int)f2bf(lo) | ((unsigned int)f2bf(hi) << 16);
}

__device__ __forceinline__ bf16x8 ldw(const float* p) {
  float4 w0 = *reinterpret_cast<const float4*>(p);
  float4 w1 = *reinterpret_cast<const float4*>(p + 4);
  bf16x8 b;
  b[0] = (short)f2bf(w0.x); b[1] = (short)f2bf(w0.y);
  b[2] = (short)f2bf(w0.z); b[3] = (short)f2bf(w0.w);
  b[4] = (short)f2bf(w1.x); b[5] = (short)f2bf(w1.y);
  b[6] = (short)f2bf(w1.z); b[7] = (short)f2bf(w1.w);
  return b;
}

// ---------------------------------------------------------------------------
// Pass 1a: per-block LDS histogram of coarse buckets (dst>>9); also converts
// x (f32) -> xh (bf16). All atomics are LDS.
// ---------------------------------------------------------------------------
__global__ __launch_bounds__(256) void bucket_hist_kernel(
    const int* __restrict__ dst, int* __restrict__ bhist,
    const float* __restrict__ x, unsigned short* __restrict__ xh) {
  __shared__ int h[NBUK];
  int tid = threadIdx.x;
  h[tid] = 0;
  __syncthreads();
  int e0 = blockIdx.x * EPB1;
  int e1 = e0 + EPB1; if (e1 > NE) e1 = NE;
  for (int e = e0 + tid; e < e1; e += 256)
    atomicAdd(&h[dst[e] >> BSHIFT], 1);
  __syncthreads();
  bhist[tid * NB1 + blockIdx.x] = h[tid];

  const int nquads = N_NODES * D / 4;
  for (int i = blockIdx.x * 256 + tid; i < nquads; i += NB1 * 256) {
    float4 v = reinterpret_cast<const float4*>(x)[i];
    ushort4 o;
    o.x = f2bf(v.x); o.y = f2bf(v.y); o.z = f2bf(v.z); o.w = f2bf(v.w);
    reinterpret_cast<ushort4*>(xh)[i] = o;
  }
}

// ---------------------------------------------------------------------------
// Blocked inclusive scan over bhist[0..NSCAN).
// ---------------------------------------------------------------------------
__global__ __launch_bounds__(SCAN_B) void scan_part(int* __restrict__ a,
                                                    int* __restrict__ bsum, int n) {
  __shared__ int s[SCAN_B];
  int i = blockIdx.x * SCAN_B + threadIdx.x;
  int v = (i < n) ? a[i] : 0;
  s[threadIdx.x] = v;
  __syncthreads();
  for (int off = 1; off < SCAN_B; off <<= 1) {
    int t = (threadIdx.x >= off) ? s[threadIdx.x - off] : 0;
    __syncthreads();
    s[threadIdx.x] += t;
    __syncthreads();
  }
  if (i < n) a[i] = s[threadIdx.x];
  if (threadIdx.x == SCAN_B - 1) bsum[blockIdx.x] = s[SCAN_B - 1];
}

__global__ __launch_bounds__(256) void scan_mid(int* __restrict__ bsum, int nb) {
  __shared__ int s[256];
  int v = (threadIdx.x < nb) ? bsum[threadIdx.x] : 0;
  s[threadIdx.x] = v;
  __syncthreads();
  for (int off = 1; off < 256; off <<= 1) {
    int t = (threadIdx.x >= off) ? s[threadIdx.x - off] : 0;
    __syncthreads();
    s[threadIdx.x] += t;
    __syncthreads();
  }
  if (threadIdx.x < nb) bsum[threadIdx.x] = s[threadIdx.x];
}

__global__ __launch_bounds__(SCAN_B) void scan_add(int* __restrict__ a,
                                                   const int* __restrict__ bsum, int n) {
  int i = blockIdx.x * SCAN_B + threadIdx.x;
  if (i >= n || blockIdx.x == 0) return;
  a[i] += bsum[blockIdx.x - 1];
}

// ---------------------------------------------------------------------------
// Pass 1b: scatter packed edges into bucket-grouped ebuk via LDS cursors.
// packed = (dst & 511) << 17 | src.
// ---------------------------------------------------------------------------
__global__ __launch_bounds__(256) void bucket_scatter_kernel(
    const int* __restrict__ src, const int* __restrict__ dst,
    const int* __restrict__ scanned, int* __restrict__ ebuk) {
  __shared__ int cur[NBUK];
  int tid = threadIdx.x;
  int idx = tid * NB1 + blockIdx.x;
  cur[tid] = (idx == 0) ? 0 : scanned[idx - 1];
  __syncthreads();
  int e0 = blockIdx.x * EPB1;
  int e1 = e0 + EPB1; if (e1 > NE) e1 = NE;
  for (int e = e0 + tid; e < e1; e += 256) {
    int d = dst[e];
    int pos = atomicAdd(&cur[d >> BSHIFT], 1);
    ebuk[pos] = ((d & (BNODES - 1)) << SRC_BITS) | src[e];
  }
}

// ---------------------------------------------------------------------------
// Pass 2: one block per coarse bucket. LDS histogram -> LDS scan ->
// row_start write -> LDS-cursor scatter of col.
// ---------------------------------------------------------------------------
__global__ __launch_bounds__(512) void bucket_csr_kernel(
    const int* __restrict__ ebuk, const int* __restrict__ scanned,
    int* __restrict__ row_start, int* __restrict__ col) {
  __shared__ int h[BNODES];
  __shared__ int cur[BNODES];
  int b = blockIdx.x;
  int tid = threadIdx.x;
  int base = (b == 0) ? 0 : scanned[b * NB1 - 1];
  int end  = scanned[(b + 1) * NB1 - 1];
  h[tid] = 0;
  __syncthreads();
  for (int p = base + tid; p < end; p += 512)
    atomicAdd(&h[ebuk[p] >> SRC_BITS], 1);
  __syncthreads();
  int orig = h[tid];
  for (int off = 1; off < 512; off <<= 1) {
    int t = (tid >= off) ? h[tid - off] : 0;
    __syncthreads();
    h[tid] += t;
    __syncthreads();
  }
  int excl = h[tid] - orig;
  int n = (b << BSHIFT) + tid;
  if (n < N_NODES) row_start[n] = base + excl;
  if (b == NBUK_USED - 1 && tid == 0) row_start[N_NODES] = end;
  cur[tid] = base + excl;
  __syncthreads();
  for (int p = base + tid; p < end; p += 512) {
    int packed = ebuk[p];
    int pos = atomicAdd(&cur[packed >> SRC_BITS], 1);
    col[pos] = packed & SRC_MASK;
  }
}

// ---------------------------------------------------------------------------
// Gather-aggregate v3 (bf16 rows, 128B each). Wave = 4 nodes sequentially;
// 8 lanes per edge-row (uint4 = 8 bf16/lane); 2-deep unroll.
// ---------------------------------------------------------------------------
__global__ __launch_bounds__(256) void aggregate_kernel(
    const unsigned short* __restrict__ feat, const int* __restrict__ row_start,
    const int* __restrict__ col, unsigned short* __restrict__ meanout) {
  int w = threadIdx.x >> 6;
  int lane = threadIdx.x & 63;
  int oct = lane >> 3;
  int sl = lane & 7;
  int nbase = blockIdx.x * 16 + w * 4;
#pragma unroll
  for (int i = 0; i < 4; ++i) {
    int node = nbase + i;
    if (node >= N_NODES) return;   // wave-uniform exit
    int r0 = row_start[node];
    int r1 = row_start[node + 1];
    float a0 = 0.f, a1 = 0.f, a2 = 0.f, a3 = 0.f;
    float a4 = 0.f, a5 = 0.f, a6 = 0.f, a7 = 0.f;
    float c0 = 0.f, c1 = 0.f, c2 = 0.f, c3 = 0.f;
    float c4 = 0.f, c5 = 0.f, c6 = 0.f, c7 = 0.f;
    int j = r0 + oct;
    for (; j + 8 < r1; j += 16) {
      int s0 = col[j];
      int s1 = col[j + 8];
      uint4 u0 = *reinterpret_cast<const uint4*>(feat + s0 * D + 8 * sl);
      uint4 u1 = *reinterpret_cast<const uint4*>(feat + s1 * D + 8 * sl);
      a0 += bflo(u0.x); a1 += bfhi(u0.x); a2 += bflo(u0.y); a3 += bfhi(u0.y);
      a4 += bflo(u0.z); a5 += bfhi(u0.z); a6 += bflo(u0.w); a7 += bfhi(u0.w);
      c0 += bflo(u1.x); c1 += bfhi(u1.x); c2 += bflo(u1.y); c3 += bfhi(u1.y);
      c4 += bflo(u1.z); c5 += bfhi(u1.z); c6 += bflo(u1.w); c7 += bfhi(u1.w);
    }
    if (j < r1) {
      int s0 = col[j];
      uint4 u0 = *reinterpret_cast<const uint4*>(feat + s0 * D + 8 * sl);
      a0 += bflo(u0.x); a1 += bfhi(u0.x); a2 += bflo(u0.y); a3 += bfhi(u0.y);
      a4 += bflo(u0.z); a5 += bfhi(u0.z); a6 += bflo(u0.w); a7 += bfhi(u0.w);
    }
    a0 += c0; a1 += c1; a2 += c2; a3 += c3;
    a4 += c4; a5 += c5; a6 += c6; a7 += c7;
#pragma unroll
    for (int d = 8; d <= 32; d <<= 1) {
      a0 += __shfl_xor(a0, d); a1 += __shfl_xor(a1, d);
      a2 += __shfl_xor(a2, d); a3 += __shfl_xor(a3, d);
      a4 += __shfl_xor(a4, d); a5 += __shfl_xor(a5, d);
      a6 += __shfl_xor(a6, d); a7 += __shfl_xor(a7, d);
    }
    if (oct == 0) {
      float inv = 1.f / fmaxf((float)(r1 - r0), 1.f);
      uint4 o;
      o.x = pack2(a0 * inv, a1 * inv);
      o.y = pack2(a2 * inv, a3 * inv);
      o.z = pack2(a4 * inv, a5 * inv);
      o.w = pack2(a6 * inv, a7 * inv);
      *reinterpret_cast<uint4*>(meanout + node * D + 8 * sl) = o;
    }
  }
}

// ---------------------------------------------------------------------------
// Layer 1 via MFMA. Output staged as bf16 in a padded LDS tile (144B rows:
// 2-way bank aliasing only), then stored with coalesced uint4 writes.
// ---------------------------------------------------------------------------
#define MT 2
__global__ __launch_bounds__(256) void layer1_mfma(
    const unsigned short* __restrict__ meanh, const unsigned short* __restrict__ xh,
    const float* __restrict__ Wl, const float* __restrict__ bl,
    const float* __restrict__ Wr,
    const float* __restrict__ g, const float* __restrict__ beta,
    const float* __restrict__ m, const float* __restrict__ v,
    unsigned short* __restrict__ h1h) {
  __shared__ float scale_s[D];
  __shared__ float shift_s[D];
  __shared__ unsigned short hts[64][72];   // bf16 out tile, rows padded to 144B
  int tid = threadIdx.x;
  if (tid < D) {
    float s = g[tid] * rsqrtf(v[tid] + BN_EPS);
    scale_s[tid] = s;
    shift_s[tid] = (bl[tid] - m[tid]) * s + beta[tid];
  }
  __syncthreads();

  int w = tid >> 6, lane = tid & 63, q = lane & 15, kg = lane >> 4;

  bf16x8 b[4][4];
#pragma unroll
  for (int f = 0; f < 4; ++f) {
    int c = f * 16 + q;
    b[0][f] = ldw(Wl + c * D + kg * 8);
    b[1][f] = ldw(Wl + c * D + 32 + kg * 8);
    b[2][f] = ldw(Wr + c * D + kg * 8);
    b[3][f] = ldw(Wr + c * D + 32 + kg * 8);
  }

#pragma unroll
  for (int mt = 0; mt < MT; ++mt) {
    int base = blockIdx.x * (64 * MT) + mt * 64 + w * 16;
    int nodeA = base + q;
    if (nodeA > N_NODES - 1) nodeA = N_NODES - 1;
    const unsigned short* mrow = meanh + (size_t)nodeA * D;
    const unsigned short* xrow = xh + (size_t)nodeA * D;
    bf16x8 a0 = *reinterpret_cast<const bf16x8*>(mrow + kg * 8);
    bf16x8 a1 = *reinterpret_cast<const bf16x8*>(mrow + 32 + kg * 8);
    bf16x8 a2 = *reinterpret_cast<const bf16x8*>(xrow + kg * 8);
    bf16x8 a3 = *reinterpret_cast<const bf16x8*>(xrow + 32 + kg * 8);

    f32x4 acc[4];
#pragma unroll
    for (int f = 0; f < 4; ++f) {
      acc[f] = (f32x4){0.f, 0.f, 0.f, 0.f};
      acc[f] = __builtin_amdgcn_mfma_f32_16x16x32_bf16(a0, b[0][f], acc[f], 0, 0, 0);
      acc[f] = __builtin_amdgcn_mfma_f32_16x16x32_bf16(a1, b[1][f], acc[f], 0, 0, 0);
      acc[f] = __builtin_amdgcn_mfma_f32_16x16x32_bf16(a2, b[2][f], acc[f], 0, 0, 0);
      acc[f] = __builtin_amdgcn_mfma_f32_16x16x32_bf16(a3, b[3][f], acc[f], 0, 0, 0);
    }

    // BN + ReLU -> bf16 LDS tile (own-wave rows only)
#pragma unroll
    for (int r = 0; r < 4; ++r)
#pragma unroll
      for (int f = 0; f < 4; ++f) {
        int c = f * 16 + q;
        hts[w * 16 + kg * 4 + r][c] =
            f2bf(fmaxf(acc[f][r] * scale_s[c] + shift_s[c], 0.f));
      }
    __syncthreads();

    // coalesced store: lane (q,kg) stores row base+q, 16B chunks kg and kg+4
    int node_s = base + q;
    const uint4* hr4 = reinterpret_cast<const uint4*>(&hts[w * 16 + q][0]);
    uint4 s0 = hr4[kg];
    uint4 s1 = hr4[kg + 4];
    if (node_s < N_NODES) {
      uint4* gout = reinterpret_cast<uint4*>(h1h + (size_t)node_s * D);
      gout[kg] = s0;
      gout[kg + 4] = s1;
    }
    __syncthreads();
  }
}

// ---------------------------------------------------------------------------
// Layer 2 via MFMA + MFMA MLP head + sigmoid.
// h2 staged as bf16 in padded LDS tile; head z = h2 @ mW1^T via 4 MFMAs
// (M=16 nodes, N=32, K=64); relu+mW2 on accumulator; shfl-reduce; sigmoid.
// ---------------------------------------------------------------------------
__global__ __launch_bounds__(256) void layer2_mfma(
    const unsigned short* __restrict__ meanh, const unsigned short* __restrict__ h1h,
    const float* __restrict__ Wl, const float* __restrict__ bl,
    const float* __restrict__ Wr,
    const float* __restrict__ g, const float* __restrict__ beta,
    const float* __restrict__ m, const float* __restrict__ v,
    const float* __restrict__ mW1, const float* __restrict__ mb1,
    const float* __restrict__ mW2, const float* __restrict__ mb2,
    float* __restrict__ out) {
  __shared__ float scale_s[D];
  __shared__ float shift_s[D];
  __shared__ unsigned short hts[64][72];
  int tid = threadIdx.x;
  if (tid < D) {
    float s = g[tid] * rsqrtf(v[tid] + BN_EPS);
    scale_s[tid] = s;
    shift_s[tid] = (bl[tid] - m[tid]) * s + beta[tid];
  }
  __syncthreads();

  int w = tid >> 6, lane = tid & 63, q = lane & 15, kg = lane >> 4;

  bf16x8 b[4][4];
#pragma unroll
  for (int f = 0; f < 4; ++f) {
    int c = f * 16 + q;
    b[0][f] = ldw(Wl + c * D + kg * 8);
    b[1][f] = ldw(Wl + c * D + 32 + kg * 8);
    b[2][f] = ldw(Wr + c * D + kg * 8);
    b[3][f] = ldw(Wr + c * D + 32 + kg * 8);
  }
  // head B frags: bh[s][f] = mW1[f*16+q][s*32 + kg*8 .. +7]
  bf16x8 bh[2][2];
#pragma unroll
  for (int f = 0; f < 2; ++f)
#pragma unroll
    for (int s = 0; s < 2; ++s)
      bh[s][f] = ldw(mW1 + (f * 16 + q) * D + s * 32 + kg * 8);
  float mw2v0 = mW2[q], mw2v1 = mW2[16 + q];
  float mb1v0 = mb1[q], mb1v1 = mb1[16 + q];
  float mb2v = mb2[0];

#pragma unroll
  for (int mt = 0; mt < MT; ++mt) {
    int base = blockIdx.x * (64 * MT) + mt * 64 + w * 16;
    int nodeA = base + q;
    if (nodeA > N_NODES - 1) nodeA = N_NODES - 1;
    const unsigned short* mrow = meanh + (size_t)nodeA * D;
    const unsigned short* xrow = h1h + (size_t)nodeA * D;
    bf16x8 a0 = *reinterpret_cast<const bf16x8*>(mrow + kg * 8);
    bf16x8 a1 = *reinterpret_cast<const bf16x8*>(mrow + 32 + kg * 8);
    bf16x8 a2 = *reinterpret_cast<const bf16x8*>(xrow + kg * 8);
    bf16x8 a3 = *reinterpret_cast<const bf16x8*>(xrow + 32 + kg * 8);

    f32x4 acc[4];
#pragma unroll
    for (int f = 0; f < 4; ++f) {
      acc[f] = (f32x4){0.f, 0.f, 0.f, 0.f};
      acc[f] = __builtin_amdgcn_mfma_f32_16x16x32_bf16(a0, b[0][f], acc[f], 0, 0, 0);
      acc[f] = __builtin_amdgcn_mfma_f32_16x16x32_bf16(a1, b[1][f], acc[f], 0, 0, 0);
      acc[f] = __builtin_amdgcn_mfma_f32_16x16x32_bf16(a2, b[2][f], acc[f], 0, 0, 0);
      acc[f] = __builtin_amdgcn_mfma_f32_16x16x32_bf16(a3, b[3][f], acc[f], 0, 0, 0);
    }

    // BN + ReLU -> bf16 LDS tile
#pragma unroll
    for (int r = 0; r < 4; ++r)
#pragma unroll
      for (int f = 0; f < 4; ++f) {
        int c = f * 16 + q;
        hts[w * 16 + kg * 4 + r][c] =
            f2bf(fmaxf(acc[f][r] * scale_s[c] + shift_s[c], 0.f));
      }
    __syncthreads();

    // head GEMM: A = hts rows (own wave's 16 nodes), K=64 (2 steps)
    const unsigned short* hrow = &hts[w * 16 + q][0];
    bf16x8 ha0 = *reinterpret_cast<const bf16x8*>(hrow + kg * 8);
    bf16x8 ha1 = *reinterpret_cast<const bf16x8*>(hrow + 32 + kg * 8);
    f32x4 az0 = (f32x4){0.f, 0.f, 0.f, 0.f};
    f32x4 az1 = (f32x4){0.f, 0.f, 0.f, 0.f};
    az0 = __builtin_amdgcn_mfma_f32_16x16x32_bf16(ha0, bh[0][0], az0, 0, 0, 0);
    az0 = __builtin_amdgcn_mfma_f32_16x16x32_bf16(ha1, bh[1][0], az0, 0, 0, 0);
    az1 = __builtin_amdgcn_mfma_f32_16x16x32_bf16(ha0, bh[0][1], az1, 0, 0, 0);
    az1 = __builtin_amdgcn_mfma_f32_16x16x32_bf16(ha1, bh[1][1], az1, 0, 0, 0);

    // per-lane: relu(z + mb1) * mW2, then reduce over the 16 q-lanes
    float ps[4];
#pragma unroll
    for (int r = 0; r < 4; ++r)
      ps[r] = fmaxf(az0[r] + mb1v0, 0.f) * mw2v0 +
              fmaxf(az1[r] + mb1v1, 0.f) * mw2v1;
#pragma unroll
    for (int d = 1; d <= 8; d <<= 1) {
      ps[0] += __shfl_xor(ps[0], d);
      ps[1] += __shfl_xor(ps[1], d);
      ps[2] += __shfl_xor(ps[2], d);
      ps[3] += __shfl_xor(ps[3], d);
    }
    if (q == 0) {
#pragma unroll
      for (int r = 0; r < 4; ++r) {
        int node = base + kg * 4 + r;
        if (node < N_NODES)
          out[node] = 1.0f / (1.0f + expf(-(ps[r] + mb2v)));
      }
    }
    __syncthreads();
  }
}

// ---------------------------------------------------------------------------
extern "C" void kernel_launch(void* const* d_in, const int* in_sizes, int n_in,
                              void* d_out, int out_size, void* d_ws, size_t ws_size,
                              hipStream_t stream) {
  const float* x    = (const float*)d_in[0];
  const int*   ei   = (const int*)d_in[1];
  const float* Wl1  = (const float*)d_in[2];
  const float* bl1  = (const float*)d_in[3];
  const float* Wr1  = (const float*)d_in[4];
  const float* g1   = (const float*)d_in[5];
  const float* be1  = (const float*)d_in[6];
  const float* m1   = (const float*)d_in[7];
  const float* v1   = (const float*)d_in[8];
  const float* Wl2  = (const float*)d_in[9];
  const float* bl2  = (const float*)d_in[10];
  const float* Wr2  = (const float*)d_in[11];
  const float* g2   = (const float*)d_in[12];
  const float* be2  = (const float*)d_in[13];
  const float* m2   = (const float*)d_in[14];
  const float* v2   = (const float*)d_in[15];
  const float* mW1  = (const float*)d_in[16];
  const float* mb1  = (const float*)d_in[17];
  const float* mW2  = (const float*)d_in[18];
  const float* mb2  = (const float*)d_in[19];
  float* out = (float*)d_out;

  const int* src = ei;
  const int* dst = ei + NE;

  // ws layout (no memsets; everything written before read):
  //   meanh | xh | h1h (bf16 N*D each) | ebuk (NE int, packed) | col (NE int)
  //   | row_start (N+16) | bhist (NSCAN) | bsum (512)
  unsigned short* meanh = (unsigned short*)d_ws;
  unsigned short* xh    = meanh + (size_t)N_NODES * D;
  unsigned short* h1h   = xh + (size_t)N_NODES * D;
  int* ebuk      = (int*)(h1h + (size_t)N_NODES * D);
  int* col       = ebuk + NE;
  int* row_start = col + NE;
  int* bhist     = row_start + (N_NODES + 16);
  int* bsum      = bhist + NSCAN;

  const int scan_blocks = NSCAN / SCAN_B;                    // 256
  const int agg_blocks  = (N_NODES + 15) / 16;
  const int gemm_blocks = (N_NODES + 64 * MT - 1) / (64 * MT);

  // --- CSR build (LDS bucket counting sort, zero global atomics) ---
  bucket_hist_kernel<<<NB1, 256, 0, stream>>>(dst, bhist, x, xh);
  scan_part<<<scan_blocks, SCAN_B, 0, stream>>>(bhist, bsum, NSCAN);
  scan_mid<<<1, 256, 0, stream>>>(bsum, scan_blocks);
  scan_add<<<scan_blocks, SCAN_B, 0, stream>>>(bhist, bsum, NSCAN);
  bucket_scatter_kernel<<<NB1, 256, 0, stream>>>(src, dst, bhist, ebuk);
  bucket_csr_kernel<<<NBUK_USED, 512, 0, stream>>>(ebuk, bhist, row_start, col);

  // --- layer 1 ---
  aggregate_kernel<<<agg_blocks, 256, 0, stream>>>(xh, row_start, col, meanh);
  layer1_mfma<<<gemm_blocks, 256, 0, stream>>>(meanh, xh, Wl1, bl1, Wr1,
                                               g1, be1, m1, v1, h1h);
  // --- layer 2 ---
  aggregate_kernel<<<agg_blocks, 256, 0, stream>>>(h1h, row_start, col, meanh);
  layer2_mfma<<<gemm_blocks, 256, 0, stream>>>(meanh, h1h, Wl2, bl2, Wr2,
                                               g2, be2, m2, v2,
                                               mW1, mb1, mW2, mb2, out);
}